// Round 10
// baseline (841.473 us; speedup 1.0000x reference)
//
#include <hip/hip_runtime.h>
#include <hip/hip_bf16.h>
#include <math.h>

#define N_NODES 50000
#define N_EDGES 800000
#define DIM 128
#define NH 4

typedef __attribute__((ext_vector_type(8))) short bf16x8;
typedef __attribute__((ext_vector_type(4))) float f32x4;
typedef unsigned int uint;
typedef unsigned short ushort;

__device__ inline short f2bf(float f) {
  __hip_bfloat16 h = __float2bfloat16(f);
  return __builtin_bit_cast(short, h);
}
__device__ inline uint pack_bf2(float lo, float hi) {
  return (uint)(ushort)f2bf(lo) | ((uint)(ushort)f2bf(hi) << 16);
}
__device__ inline float bflo(uint u) { return __builtin_bit_cast(float, u << 16); }
__device__ inline float bfhi(uint u) { return __builtin_bit_cast(float, u & 0xffff0000u); }

// ---------------- BN stats (node): per-column sum & sumsq ----------------
__global__ __launch_bounds__(256) void bn_stats_kernel(
    const float* __restrict__ x, int M, float* __restrict__ out) {
  __shared__ float s_sum[DIM];
  __shared__ float s_sq[DIM];
  int t = threadIdx.x;
  if (t < DIM) { s_sum[t] = 0.f; s_sq[t] = 0.f; }
  __syncthreads();
  int c4 = (t & 31) * 4;
  int rg = t >> 5;
  float sum0=0,sum1=0,sum2=0,sum3=0, sq0=0,sq1=0,sq2=0,sq3=0;
  for (long row = (long)blockIdx.x * 8 + rg; row < M; row += (long)gridDim.x * 8) {
    float4 v = *reinterpret_cast<const float4*>(x + row * DIM + c4);
    sum0 += v.x; sq0 += v.x * v.x;
    sum1 += v.y; sq1 += v.y * v.y;
    sum2 += v.z; sq2 += v.z * v.z;
    sum3 += v.w; sq3 += v.w * v.w;
  }
  atomicAdd(&s_sum[c4 + 0], sum0); atomicAdd(&s_sq[c4 + 0], sq0);
  atomicAdd(&s_sum[c4 + 1], sum1); atomicAdd(&s_sq[c4 + 1], sq1);
  atomicAdd(&s_sum[c4 + 2], sum2); atomicAdd(&s_sq[c4 + 2], sq2);
  atomicAdd(&s_sum[c4 + 3], sum3); atomicAdd(&s_sq[c4 + 3], sq3);
  __syncthreads();
  if (t < DIM) {
    atomicAdd(&out[t], s_sum[t]);
    atomicAdd(&out[DIM + t], s_sq[t]);
  }
}

// ---------------- BN stats (edge) + fused dst histogram ----------------
__global__ __launch_bounds__(256) void bn_stats_hist_kernel(
    const float* __restrict__ x, const int* __restrict__ dst,
    float* __restrict__ out, int* __restrict__ deg) {
  __shared__ float s_sum[DIM];
  __shared__ float s_sq[DIM];
  int t = threadIdx.x;
  if (t < DIM) { s_sum[t] = 0.f; s_sq[t] = 0.f; }
  __syncthreads();
  for (long i = (long)blockIdx.x * 256 + t; i < N_EDGES; i += (long)gridDim.x * 256) {
    atomicAdd(&deg[dst[i]], 1);
  }
  int c4 = (t & 31) * 4;
  int rg = t >> 5;
  float sum0=0,sum1=0,sum2=0,sum3=0, sq0=0,sq1=0,sq2=0,sq3=0;
  for (long row = (long)blockIdx.x * 8 + rg; row < N_EDGES; row += (long)gridDim.x * 8) {
    float4 v = *reinterpret_cast<const float4*>(x + row * DIM + c4);
    sum0 += v.x; sq0 += v.x * v.x;
    sum1 += v.y; sq1 += v.y * v.y;
    sum2 += v.z; sq2 += v.z * v.z;
    sum3 += v.w; sq3 += v.w * v.w;
  }
  atomicAdd(&s_sum[c4 + 0], sum0); atomicAdd(&s_sq[c4 + 0], sq0);
  atomicAdd(&s_sum[c4 + 1], sum1); atomicAdd(&s_sq[c4 + 1], sq1);
  atomicAdd(&s_sum[c4 + 2], sum2); atomicAdd(&s_sq[c4 + 2], sq2);
  atomicAdd(&s_sum[c4 + 3], sum3); atomicAdd(&s_sq[c4 + 3], sq3);
  __syncthreads();
  if (t < DIM) {
    atomicAdd(&out[t], s_sum[t]);
    atomicAdd(&out[DIM + t], s_sq[t]);
  }
}

// ---- fold: blocks 0-3 = BN-folded Wq/Wk/Wv/We; block 4 = OwT; block 5 = W2T ----
__global__ __launch_bounds__(1024) void fold6_kernel(
    const float* __restrict__ Wq, const float* __restrict__ Wk,
    const float* __restrict__ Wv, const float* __restrict__ We,
    const float* __restrict__ Ow, const float* __restrict__ W2,
    const float* __restrict__ stats_n, const float* __restrict__ stats_e,
    const float* __restrict__ g1n, const float* __restrict__ b1n,
    const float* __restrict__ g1e, const float* __restrict__ b1e, float inv_s,
    short* __restrict__ WqT, short* __restrict__ WkT,
    short* __restrict__ WvT, short* __restrict__ WeT,
    short* __restrict__ OwT, short* __restrict__ W2T,
    float* __restrict__ bq, float* __restrict__ bk,
    float* __restrict__ bv, float* __restrict__ be) {
  int b = blockIdx.x;
  int t = threadIdx.x;
  if (b == 4) {
    int d = t & 127, kg = t >> 7;
#pragma unroll
    for (int j = 0; j < 16; ++j) {
      int k = kg * 16 + j;
      OwT[d * DIM + k] = f2bf(Ow[k * DIM + d]);
    }
    return;
  }
  if (b == 5) {
    int d = t & 127, kg = t >> 7;
#pragma unroll
    for (int j = 0; j < 32; ++j) {
      int k = kg * 32 + j;
      W2T[d * 256 + k] = f2bf(W2[k * DIM + d]);
    }
    return;
  }
  __shared__ float red[8][DIM];
  __shared__ float sab[DIM], sbb[DIM];
  const float* W = (b == 0) ? Wq : (b == 1) ? Wk : (b == 2) ? Wv : We;
  const float* stats = (b == 3) ? stats_e : stats_n;
  const float* gamma = (b == 3) ? g1e : g1n;
  const float* beta  = (b == 3) ? b1e : b1n;
  float M            = (b == 3) ? (float)N_EDGES : (float)N_NODES;
  float scale = (b == 1) ? inv_s : 1.f;
  short* WT = (b == 0) ? WqT : (b == 1) ? WkT : (b == 2) ? WvT : WeT;
  float* bias = (b == 0) ? bq : (b == 1) ? bk : (b == 2) ? bv : be;
  if (t < DIM) {
    float mean = stats[t] / M;
    float var = stats[DIM + t] / M - mean * mean;
    float a = gamma[t] * rsqrtf(var + 1e-5f);
    sab[t] = a;
    sbb[t] = beta[t] - mean * a;
  }
  __syncthreads();
  int d = t & 127, kg = t >> 7;
  int ct = d >> 4, lr = d & 15;
  int L = (ct >> 1) * 32 + lr * 2 + (ct & 1);
  float bacc = 0.f;
#pragma unroll
  for (int j = 0; j < 16; ++j) {
    int k = kg * 16 + j;
    float wv = W[k * DIM + L];
    WT[d * DIM + k] = f2bf(scale * sab[k] * wv);
    bacc += sbb[k] * wv;
  }
  red[kg][d] = bacc;
  __syncthreads();
  if (kg == 0) {
    float s = 0.f;
#pragma unroll
    for (int j = 0; j < 8; ++j) s += red[j][d];
    bias[d] = scale * s;
  }
}

// ---- fold BN2 into W1: parallel (16 blocks x 256 thr, LDS bias reduce) ----
__global__ __launch_bounds__(256) void fold_w1_kernel(
    const float* __restrict__ W1, const float* __restrict__ stats_h,
    const float* __restrict__ g2, const float* __restrict__ b2,
    short* __restrict__ W1F, float* __restrict__ bias1) {
  __shared__ float sab[DIM], sbb[DIM];
  __shared__ float red[16][17];
  int t = threadIdx.x;
  if (t < DIM) {
    float mean = stats_h[t] / (float)N_NODES;
    float var = stats_h[DIM + t] / (float)N_NODES - mean * mean;
    float a = g2[t] * rsqrtf(var + 1e-5f);
    sab[t] = a;
    sbb[t] = b2[t] - mean * a;
  }
  __syncthreads();
  int dl = t & 15, kg = t >> 4;
  int d = blockIdx.x * 16 + dl;
  float bacc = 0.f;
#pragma unroll
  for (int j = 0; j < 8; ++j) {
    int k = kg * 8 + j;
    float wv = W1[k * 256 + d];
    W1F[d * DIM + k] = f2bf(sab[k] * wv);
    bacc += sbb[k] * wv;
  }
  red[dl][kg] = bacc;
  __syncthreads();
  if (kg == 0) {
    float s = 0.f;
#pragma unroll
    for (int j = 0; j < 16; ++j) s += red[dl][j];
    bias1[d] = s;
  }
}

// ---- load A fragments (4 k-steps) for 16 rows at m0, fp32->bf16 ----
__device__ inline void load_a_frags(const float* __restrict__ X, long m0,
                                    int lr, int lg, bf16x8 a[4]) {
#pragma unroll
  for (int ks = 0; ks < 4; ++ks) {
    const float* p = X + (m0 + lr) * DIM + ks * 32 + lg * 8;
    float4 v0 = *reinterpret_cast<const float4*>(p);
    float4 v1 = *reinterpret_cast<const float4*>(p + 4);
    bf16x8 af;
    af[0] = f2bf(v0.x); af[1] = f2bf(v0.y); af[2] = f2bf(v0.z); af[3] = f2bf(v0.w);
    af[4] = f2bf(v1.x); af[5] = f2bf(v1.y); af[6] = f2bf(v1.z); af[7] = f2bf(v1.w);
    a[ks] = af;
  }
}

// ---------------- QKV via MFMA -> packed bf16 ----------------
__global__ __launch_bounds__(256) void qkv_mfma_kernel(
    const float* __restrict__ nf,
    const short* __restrict__ WqT, const short* __restrict__ WkT, const short* __restrict__ WvT,
    const float* __restrict__ bq, const float* __restrict__ bk, const float* __restrict__ bv,
    ushort* __restrict__ Qb, ushort* __restrict__ Kb, ushort* __restrict__ Vb) {
  int t = threadIdx.x;
  int w = t >> 6, l = t & 63;
  int lr = l & 15, lg = l >> 4;
  long m0 = (long)blockIdx.x * 64 + w * 16;
  if (m0 >= N_NODES) return;
  bf16x8 a[4];
  load_a_frags(nf, m0, lr, lg, a);
  const short* Ws[3] = {WqT, WkT, WvT};
  const float* bs[3] = {bq, bk, bv};
  ushort* Os[3] = {Qb, Kb, Vb};
#pragma unroll 1
  for (int m = 0; m < 3; ++m) {
    const short* WT = Ws[m];
    f32x4 acc[8];
#pragma unroll
    for (int ct = 0; ct < 8; ++ct) acc[ct] = (f32x4){0.f, 0.f, 0.f, 0.f};
#pragma unroll
    for (int ct = 0; ct < 8; ++ct) {
#pragma unroll
      for (int ks = 0; ks < 4; ++ks) {
        bf16x8 b = *reinterpret_cast<const bf16x8*>(WT + (ct * 16 + lr) * DIM + ks * 32 + lg * 8);
        acc[ct] = __builtin_amdgcn_mfma_f32_16x16x32_bf16(a[ks], b, acc[ct], 0, 0, 0);
      }
    }
    const float* bb = bs[m];
    ushort* O = Os[m];
#pragma unroll
    for (int h = 0; h < 4; ++h) {
      float b0 = bb[(2 * h) * 16 + lr];
      float b1 = bb[(2 * h + 1) * 16 + lr];
#pragma unroll
      for (int r = 0; r < 4; ++r) {
        uint u = pack_bf2(acc[2 * h][r] + b0, acc[2 * h + 1][r] + b1);
        *reinterpret_cast<uint*>(O + (m0 + lg * 4 + r) * DIM + h * 32 + lr * 2) = u;
      }
    }
  }
}

// ---------------- CSR scan + scatter (int4 entries: src, e, dst, 0) ----------------
#define SCAN_T 1024
#define PER_T 49
__global__ __launch_bounds__(SCAN_T) void scan_kernel(
    const int* __restrict__ deg, int* __restrict__ row_start, int* __restrict__ cursor) {
  __shared__ int ps[SCAN_T];
  int t = threadIdx.x;
  int base = t * PER_T;
  int lsum = 0;
  int local[PER_T];
#pragma unroll
  for (int j = 0; j < PER_T; ++j) {
    int idx = base + j;
    int d = (idx < N_NODES) ? deg[idx] : 0;
    local[j] = lsum;
    lsum += d;
  }
  ps[t] = lsum;
  __syncthreads();
  for (int off = 1; off < SCAN_T; off <<= 1) {
    int v = (t >= off) ? ps[t - off] : 0;
    __syncthreads();
    ps[t] += v;
    __syncthreads();
  }
  int prefix = (t == 0) ? 0 : ps[t - 1];
#pragma unroll
  for (int j = 0; j < PER_T; ++j) {
    int idx = base + j;
    if (idx < N_NODES) {
      int v = prefix + local[j];
      row_start[idx] = v;
      cursor[idx] = v;
    }
  }
  if (t == SCAN_T - 1) row_start[N_NODES] = ps[SCAN_T - 1];
}

__global__ __launch_bounds__(256) void scatter_kernel(
    const int* __restrict__ src, const int* __restrict__ dst,
    int* __restrict__ cursor, int4* __restrict__ csr4) {
  int i = blockIdx.x * 256 + threadIdx.x;
  int d = dst[i];
  int pos = atomicAdd(&cursor[d], 1);
  csr4[pos] = make_int4(src[i], i, d, 0);
}

// ------- edge score in CSR order: Q gathers L2-local, s writes sequential -------
#define ES_GRID 2048
__global__ __launch_bounds__(256) void edge_score_kernel(
    const float* __restrict__ ef,
    const int4* __restrict__ csr4,
    const short* __restrict__ WeT, const float* __restrict__ be,
    const ushort* __restrict__ Qb, const ushort* __restrict__ Kb,
    float* __restrict__ s_csr) {
  const int NT = N_EDGES / 64;     // 12500
  const int CHUNK = (NT + 7) / 8;  // 1563 tiles per XCD
  int t = threadIdx.x;
  int w = t >> 6, l = t & 63;
  int lr = l & 15, lg = l >> 4;
  int bid = blockIdx.x;
  int xcd = bid & 7, j0 = bid >> 3;        // 256 blocks per XCD
  int start = xcd * CHUNK + j0;
  int end = ((xcd + 1) * CHUNK < NT) ? (xcd + 1) * CHUNK : NT;
  float ber[8];
#pragma unroll
  for (int ct = 0; ct < 8; ++ct) ber[ct] = be[ct * 16 + lr];

  for (int tile = start; tile < end; tile += 256) {
    long base = (long)tile * 64 + w * 16;
    // each lane owns entry (base + lr): (src, e, dst, 0)
    int4 ent = csr4[base + lr];
    // broadcast src/dst for this lane-group's 4 score rows (entries lg*4+r)
    int sn[4], dn[4];
#pragma unroll
    for (int r = 0; r < 4; ++r) {
      sn[r] = __shfl(ent.x, lg * 4 + r);
      dn[r] = __shfl(ent.z, lg * 4 + r);
    }
    // issue K/Q gathers (Q rows repeat within dst-sorted tile -> L2 hits)
    uint Kg[4][4], Qg[4][4];
#pragma unroll
    for (int r = 0; r < 4; ++r) {
#pragma unroll
      for (int h = 0; h < 4; ++h) {
        Kg[r][h] = *reinterpret_cast<const uint*>(Kb + (long)sn[r] * DIM + h * 32 + lr * 2);
        Qg[r][h] = *reinterpret_cast<const uint*>(Qb + (long)dn[r] * DIM + h * 32 + lr * 2);
      }
    }
    // load own ef row (edge id = ent.y), cvt to bf16 frags
    bf16x8 a[4];
    {
      const float* rowp = ef + (long)ent.y * DIM;
#pragma unroll
      for (int ks = 0; ks < 4; ++ks) {
        const float* p = rowp + ks * 32 + lg * 8;
        f32x4 v0 = *reinterpret_cast<const f32x4*>(p);
        f32x4 v1 = *reinterpret_cast<const f32x4*>(p + 4);
        bf16x8 t8;
        t8[0] = f2bf(v0.x); t8[1] = f2bf(v0.y); t8[2] = f2bf(v0.z); t8[3] = f2bf(v0.w);
        t8[4] = f2bf(v1.x); t8[5] = f2bf(v1.y); t8[6] = f2bf(v1.z); t8[7] = f2bf(v1.w);
        a[ks] = t8;
      }
    }
    // MFMA projection
    f32x4 acc[8];
#pragma unroll
    for (int ct = 0; ct < 8; ++ct) acc[ct] = (f32x4){0.f, 0.f, 0.f, 0.f};
#pragma unroll
    for (int ct = 0; ct < 8; ++ct) {
#pragma unroll
      for (int ks = 0; ks < 4; ++ks) {
        bf16x8 b = *reinterpret_cast<const bf16x8*>(WeT + (ct * 16 + lr) * DIM + ks * 32 + lg * 8);
        acc[ct] = __builtin_amdgcn_mfma_f32_16x16x32_bf16(a[ks], b, acc[ct], 0, 0, 0);
      }
    }
    // score + reduce + sequential store at CSR position
#pragma unroll
    for (int r = 0; r < 4; ++r) {
      float hs0, hs1, hs2, hs3;
      {
        float h0, h1, h2, h3;
#pragma unroll
        for (int h = 0; h < 4; ++h) {
          float k0 = bflo(Kg[r][h]), k1 = bfhi(Kg[r][h]);
          float q0 = bflo(Qg[r][h]), q1 = bfhi(Qg[r][h]);
          float pe0 = acc[2 * h][r] + ber[2 * h];
          float pe1 = acc[2 * h + 1][r] + ber[2 * h + 1];
          float v = fminf(fmaxf(k0 * q0, -5.f), 5.f) * pe0
                  + fminf(fmaxf(k1 * q1, -5.f), 5.f) * pe1;
          if (h == 0) h0 = v; else if (h == 1) h1 = v; else if (h == 2) h2 = v; else h3 = v;
        }
        hs0 = h0; hs1 = h1; hs2 = h2; hs3 = h3;
      }
#pragma unroll
      for (int m2 = 8; m2 >= 1; m2 >>= 1) {
        hs0 += __shfl_xor(hs0, m2);
        hs1 += __shfl_xor(hs1, m2);
        hs2 += __shfl_xor(hs2, m2);
        hs3 += __shfl_xor(hs3, m2);
      }
      if (lr < 4) {
        float myh = (lr == 0) ? hs0 : ((lr == 1) ? hs1 : ((lr == 2) ? hs2 : hs3));
        s_csr[(base + lg * 4 + r) * 4 + lr] = __expf(fminf(fmaxf(myh, -5.f), 5.f));
      }
    }
  }
}

// ------- aggregate: one wave per dst node; sequential csr4 + s_csr, random V -------
__global__ __launch_bounds__(256) void aggregate_kernel(
    const int* __restrict__ row_start, const int4* __restrict__ csr4,
    const float* __restrict__ s_csr, const ushort* __restrict__ Vb,
    ushort* __restrict__ haggb) {
  int t = threadIdx.x;
  int w = t >> 6, l = t & 63;
  int n = blockIdx.x * 4 + w;
  int r0 = row_start[n], r1 = row_start[n + 1];
  int h = l >> 4;
  float a0 = 0.f, a1 = 0.f, zacc = 0.f;
  int idx = r0;
  for (; idx + 4 <= r1; idx += 4) {
    int sn[4]; float sv[4]; uint uv[4];
#pragma unroll
    for (int jj = 0; jj < 4; ++jj) sn[jj] = csr4[idx + jj].x;
#pragma unroll
    for (int jj = 0; jj < 4; ++jj) {
      sv[jj] = s_csr[(long)(idx + jj) * 4 + h];
      uv[jj] = *reinterpret_cast<const uint*>(Vb + (long)sn[jj] * DIM + l * 2);
    }
#pragma unroll
    for (int jj = 0; jj < 4; ++jj) {
      a0 += sv[jj] * bflo(uv[jj]);
      a1 += sv[jj] * bfhi(uv[jj]);
      zacc += sv[jj];
    }
  }
  for (; idx < r1; ++idx) {
    int sn = csr4[idx].x;
    float sa = s_csr[(long)idx * 4 + h];
    uint ua = *reinterpret_cast<const uint*>(Vb + (long)sn * DIM + l * 2);
    a0 += sa * bflo(ua);
    a1 += sa * bfhi(ua);
    zacc += sa;
  }
  float inv = 1.f / (zacc + 1e-6f);
  *reinterpret_cast<uint*>(haggb + (long)n * DIM + l * 2) = pack_bf2(a0 * inv, a1 * inv);
}

// ---------------- attnout via MFMA: hres = h_in1 + hagg @ Ow + Ob; BN2 stats ----------------
__global__ __launch_bounds__(256) void attnout_mfma_kernel(
    const ushort* __restrict__ haggb, const short* __restrict__ OwT,
    const float* __restrict__ Ob, const float* __restrict__ h_in1,
    float* __restrict__ hres, float* __restrict__ stats2) {
  int t = threadIdx.x;
  int w = t >> 6, l = t & 63;
  int lr = l & 15, lg = l >> 4;
  long m0 = (long)blockIdx.x * 64 + w * 16;
  if (m0 >= N_NODES) return;
  bf16x8 a[4];
#pragma unroll
  for (int ks = 0; ks < 4; ++ks) {
    a[ks] = *reinterpret_cast<const bf16x8*>(haggb + (m0 + lr) * DIM + ks * 32 + lg * 8);
  }
  f32x4 acc[8];
#pragma unroll
  for (int ct = 0; ct < 8; ++ct) acc[ct] = (f32x4){0.f, 0.f, 0.f, 0.f};
#pragma unroll
  for (int ct = 0; ct < 8; ++ct) {
#pragma unroll
    for (int ks = 0; ks < 4; ++ks) {
      bf16x8 b = *reinterpret_cast<const bf16x8*>(OwT + (ct * 16 + lr) * DIM + ks * 32 + lg * 8);
      acc[ct] = __builtin_amdgcn_mfma_f32_16x16x32_bf16(a[ks], b, acc[ct], 0, 0, 0);
    }
  }
#pragma unroll
  for (int ct = 0; ct < 8; ++ct) {
    float ob = Ob[ct * 16 + lr];
    float ls = 0.f, lq = 0.f;
#pragma unroll
    for (int r = 0; r < 4; ++r) {
      long idx = (m0 + lg * 4 + r) * DIM + ct * 16 + lr;
      float hv = h_in1[idx] + acc[ct][r] + ob;
      hres[idx] = hv;
      ls += hv; lq += hv * hv;
    }
    ls += __shfl_xor(ls, 16); ls += __shfl_xor(ls, 32);
    lq += __shfl_xor(lq, 16); lq += __shfl_xor(lq, 32);
    if (lg == 0) {
      atomicAdd(&stats2[ct * 16 + lr], ls);
      atomicAdd(&stats2[DIM + ct * 16 + lr], lq);
    }
  }
}

// ---------------- MLP via MFMA: out = hres + silu(BN2(hres) @ W1) @ W2 ----------------
__global__ __launch_bounds__(256) void mlp_mfma_kernel(
    const float* __restrict__ hres, const short* __restrict__ W1F,
    const float* __restrict__ bias1, const short* __restrict__ W2T,
    float* __restrict__ out) {
  __shared__ short mid[64][264];  // padded: 2-way bank conflicts only
  int t = threadIdx.x;
  int w = t >> 6, l = t & 63;
  int lr = l & 15, lg = l >> 4;
  long m0 = (long)blockIdx.x * 64 + w * 16;
  if (m0 >= N_NODES) return;
  bf16x8 a1[4];
  load_a_frags(hres, m0, lr, lg, a1);
#pragma unroll
  for (int ct = 0; ct < 16; ++ct) {
    f32x4 acc = (f32x4){0.f, 0.f, 0.f, 0.f};
#pragma unroll
    for (int ks = 0; ks < 4; ++ks) {
      bf16x8 b = *reinterpret_cast<const bf16x8*>(W1F + (ct * 16 + lr) * DIM + ks * 32 + lg * 8);
      acc = __builtin_amdgcn_mfma_f32_16x16x32_bf16(a1[ks], b, acc, 0, 0, 0);
    }
    float bb = bias1[ct * 16 + lr];
#pragma unroll
    for (int r = 0; r < 4; ++r) {
      float x = acc[r] + bb;
      float sl = x / (1.f + __expf(-x));
      mid[w * 16 + lg * 4 + r][ct * 16 + lr] = f2bf(sl);
    }
  }
  bf16x8 a2[8];
#pragma unroll
  for (int ks = 0; ks < 8; ++ks) {
    a2[ks] = *reinterpret_cast<const bf16x8*>(&mid[w * 16 + lr][ks * 32 + lg * 8]);
  }
#pragma unroll
  for (int ct = 0; ct < 8; ++ct) {
    f32x4 acc = (f32x4){0.f, 0.f, 0.f, 0.f};
#pragma unroll
    for (int ks = 0; ks < 8; ++ks) {
      bf16x8 b = *reinterpret_cast<const bf16x8*>(W2T + (ct * 16 + lr) * 256 + ks * 32 + lg * 8);
      acc = __builtin_amdgcn_mfma_f32_16x16x32_bf16(a2[ks], b, acc, 0, 0, 0);
    }
#pragma unroll
    for (int r = 0; r < 4; ++r) {
      long idx = (m0 + lg * 4 + r) * DIM + ct * 16 + lr;
      out[idx] = hres[idx] + acc[r];
    }
  }
}

extern "C" void kernel_launch(void* const* d_in, const int* in_sizes, int n_in,
                              void* d_out, int out_size, void* d_ws, size_t ws_size,
                              hipStream_t stream) {
  const float* node_feats = (const float*)d_in[0];
  const float* edge_feats = (const float*)d_in[1];
  const int* src = (const int*)d_in[2];
  const int* dst = (const int*)d_in[3];
  const float* Wq = (const float*)d_in[4];
  const float* Wk = (const float*)d_in[5];
  const float* Wv = (const float*)d_in[6];
  const float* We = (const float*)d_in[7];
  const float* Ow = (const float*)d_in[8];
  const float* Ob = (const float*)d_in[9];
  const float* g1n = (const float*)d_in[10];
  const float* b1n = (const float*)d_in[11];
  const float* g1e = (const float*)d_in[12];
  const float* b1e = (const float*)d_in[13];
  const float* g2 = (const float*)d_in[14];
  const float* b2 = (const float*)d_in[15];
  const float* W1 = (const float*)d_in[16];
  const float* W2 = (const float*)d_in[17];
  float* out = (float*)d_out;
  float* w = (float*)d_ws;

  float* stats_n = w + 0;
  float* stats_e = w + 256;
  float* stats_h = w + 512;
  float* bq = w + 1536;
  float* bk = w + 1664;
  float* bv = w + 1792;
  float* be = w + 1920;
  short* WqT = (short*)(w + 2048);    // 128x128 bf16 = 8192 floats
  short* WkT = (short*)(w + 10240);
  short* WvT = (short*)(w + 18432);
  short* WeT = (short*)(w + 26624);
  short* OwT = (short*)(w + 34816);   // 8192 floats
  short* W1F = (short*)(w + 43008);   // 256x128 bf16 = 16384 floats
  short* W2T = (short*)(w + 59392);   // 128x256 bf16 = 16384 floats
  float* bias1 = w + 75776;           // 256
  ushort* Qb = (ushort*)(w + 76032);  // N*128 bf16 = 3.2M floats
  ushort* Kb = (ushort*)(w + 3276032);
  ushort* Vb = (ushort*)(w + 6476032);
  float* s_csr = w + 9676032;         // E*4 floats (CSR-ordered)
  int* deg = (int*)(w + 12876032);
  int* row_start = deg + 50048;       // 50001 (padded 50064)
  int* cursor = row_start + 50064;    // 50000 (padded 50048)
  int4* csr4 = (int4*)(w + 13026192); // E int4 = 3.2M floats (16B-aligned)
  ushort* haggb = (ushort*)(w + 76032);  // overlays Qb (dead after edge_score)

  const float inv_s = 0.17677669529663687f;  // 1/sqrt(32), folded into K

  hipMemsetAsync(w, 0, 768 * sizeof(float), stream);
  hipMemsetAsync(deg, 0, 50000 * sizeof(int), stream);

  bn_stats_kernel<<<512, 256, 0, stream>>>(node_feats, N_NODES, stats_n);
  bn_stats_hist_kernel<<<2048, 256, 0, stream>>>(edge_feats, dst, stats_e, deg);
  fold6_kernel<<<6, 1024, 0, stream>>>(Wq, Wk, Wv, We, Ow, W2, stats_n, stats_e,
                                       g1n, b1n, g1e, b1e, inv_s,
                                       WqT, WkT, WvT, WeT, OwT, W2T, bq, bk, bv, be);
  scan_kernel<<<1, SCAN_T, 0, stream>>>(deg, row_start, cursor);
  scatter_kernel<<<N_EDGES / 256, 256, 0, stream>>>(src, dst, cursor, csr4);

  qkv_mfma_kernel<<<(N_NODES + 63) / 64, 256, 0, stream>>>(
      node_feats, WqT, WkT, WvT, bq, bk, bv, Qb, Kb, Vb);
  edge_score_kernel<<<ES_GRID, 256, 0, stream>>>(
      edge_feats, csr4, WeT, be, Qb, Kb, s_csr);
  aggregate_kernel<<<N_NODES / 4, 256, 0, stream>>>(row_start, csr4, s_csr, Vb, haggb);
  attnout_mfma_kernel<<<(N_NODES + 63) / 64, 256, 0, stream>>>(
      haggb, OwT, Ob, node_feats, out, stats_h);
  fold_w1_kernel<<<16, 256, 0, stream>>>(W1, stats_h, g2, b2, W1F, bias1);
  mlp_mfma_kernel<<<(N_NODES + 63) / 64, 256, 0, stream>>>(out, W1F, bias1, W2T, out);
}

// Round 11
// 815.203 us; speedup vs baseline: 1.0322x; 1.0322x over previous
//
#include <hip/hip_runtime.h>
#include <hip/hip_bf16.h>
#include <math.h>

#define N_NODES 50000
#define N_EDGES 800000
#define DIM 128
#define NH 4

typedef __attribute__((ext_vector_type(8))) short bf16x8;
typedef __attribute__((ext_vector_type(4))) float f32x4;
typedef unsigned int uint;
typedef unsigned short ushort;

__device__ inline short f2bf(float f) {
  __hip_bfloat16 h = __float2bfloat16(f);
  return __builtin_bit_cast(short, h);
}
__device__ inline uint pack_bf2(float lo, float hi) {
  return (uint)(ushort)f2bf(lo) | ((uint)(ushort)f2bf(hi) << 16);
}
__device__ inline float bflo(uint u) { return __builtin_bit_cast(float, u << 16); }
__device__ inline float bfhi(uint u) { return __builtin_bit_cast(float, u & 0xffff0000u); }

// ---- fused stats: blocks <512 node stats; blocks >=512 edge stats + hist + bf16 stage ----
__global__ __launch_bounds__(256) void stats_all_kernel(
    const float* __restrict__ nf, const float* __restrict__ ef,
    const int* __restrict__ dst,
    float* __restrict__ stats_n, float* __restrict__ stats_e,
    int* __restrict__ deg, ushort* __restrict__ efb) {
  __shared__ float s_sum[DIM];
  __shared__ float s_sq[DIM];
  int t = threadIdx.x;
  if (t < DIM) { s_sum[t] = 0.f; s_sq[t] = 0.f; }
  __syncthreads();
  int c4 = (t & 31) * 4;
  int rg = t >> 5;
  float sum0=0,sum1=0,sum2=0,sum3=0, sq0=0,sq1=0,sq2=0,sq3=0;
  if (blockIdx.x < 512) {
    // ---- node stats ----
    for (long row = (long)blockIdx.x * 8 + rg; row < N_NODES; row += 512L * 8) {
      float4 v = *reinterpret_cast<const float4*>(nf + row * DIM + c4);
      sum0 += v.x; sq0 += v.x * v.x;
      sum1 += v.y; sq1 += v.y * v.y;
      sum2 += v.z; sq2 += v.z * v.z;
      sum3 += v.w; sq3 += v.w * v.w;
    }
    atomicAdd(&s_sum[c4 + 0], sum0); atomicAdd(&s_sq[c4 + 0], sq0);
    atomicAdd(&s_sum[c4 + 1], sum1); atomicAdd(&s_sq[c4 + 1], sq1);
    atomicAdd(&s_sum[c4 + 2], sum2); atomicAdd(&s_sq[c4 + 2], sq2);
    atomicAdd(&s_sum[c4 + 3], sum3); atomicAdd(&s_sq[c4 + 3], sq3);
    __syncthreads();
    if (t < DIM) {
      atomicAdd(&stats_n[t], s_sum[t]);
      atomicAdd(&stats_n[DIM + t], s_sq[t]);
    }
  } else {
    // ---- edge stats + histogram + bf16 staging ----
    long bid2 = blockIdx.x - 512;  // 0..2047
    for (long i = bid2 * 256 + t; i < N_EDGES; i += 2048L * 256) {
      atomicAdd(&deg[dst[i]], 1);
    }
    for (long row = bid2 * 8 + rg; row < N_EDGES; row += 2048L * 8) {
      float4 v = *reinterpret_cast<const float4*>(ef + row * DIM + c4);
      sum0 += v.x; sq0 += v.x * v.x;
      sum1 += v.y; sq1 += v.y * v.y;
      sum2 += v.z; sq2 += v.z * v.z;
      sum3 += v.w; sq3 += v.w * v.w;
      uint2 p;
      p.x = pack_bf2(v.x, v.y);
      p.y = pack_bf2(v.z, v.w);
      *reinterpret_cast<uint2*>(efb + row * DIM + c4) = p;
    }
    atomicAdd(&s_sum[c4 + 0], sum0); atomicAdd(&s_sq[c4 + 0], sq0);
    atomicAdd(&s_sum[c4 + 1], sum1); atomicAdd(&s_sq[c4 + 1], sq1);
    atomicAdd(&s_sum[c4 + 2], sum2); atomicAdd(&s_sq[c4 + 2], sq2);
    atomicAdd(&s_sum[c4 + 3], sum3); atomicAdd(&s_sq[c4 + 3], sq3);
    __syncthreads();
    if (t < DIM) {
      atomicAdd(&stats_e[t], s_sum[t]);
      atomicAdd(&stats_e[DIM + t], s_sq[t]);
    }
  }
}

// ---- fold: blocks 0-3 = BN-folded Wq/Wk/Wv/We; block 4 = OwT; block 5 = W2T ----
__global__ __launch_bounds__(1024) void fold6_kernel(
    const float* __restrict__ Wq, const float* __restrict__ Wk,
    const float* __restrict__ Wv, const float* __restrict__ We,
    const float* __restrict__ Ow, const float* __restrict__ W2,
    const float* __restrict__ stats_n, const float* __restrict__ stats_e,
    const float* __restrict__ g1n, const float* __restrict__ b1n,
    const float* __restrict__ g1e, const float* __restrict__ b1e, float inv_s,
    short* __restrict__ WqT, short* __restrict__ WkT,
    short* __restrict__ WvT, short* __restrict__ WeT,
    short* __restrict__ OwT, short* __restrict__ W2T,
    float* __restrict__ bq, float* __restrict__ bk,
    float* __restrict__ bv, float* __restrict__ be) {
  int b = blockIdx.x;
  int t = threadIdx.x;
  if (b == 4) {
    int d = t & 127, kg = t >> 7;
#pragma unroll
    for (int j = 0; j < 16; ++j) {
      int k = kg * 16 + j;
      OwT[d * DIM + k] = f2bf(Ow[k * DIM + d]);
    }
    return;
  }
  if (b == 5) {
    int d = t & 127, kg = t >> 7;
#pragma unroll
    for (int j = 0; j < 32; ++j) {
      int k = kg * 32 + j;
      W2T[d * 256 + k] = f2bf(W2[k * DIM + d]);
    }
    return;
  }
  __shared__ float red[8][DIM];
  __shared__ float sab[DIM], sbb[DIM];
  const float* W = (b == 0) ? Wq : (b == 1) ? Wk : (b == 2) ? Wv : We;
  const float* stats = (b == 3) ? stats_e : stats_n;
  const float* gamma = (b == 3) ? g1e : g1n;
  const float* beta  = (b == 3) ? b1e : b1n;
  float M            = (b == 3) ? (float)N_EDGES : (float)N_NODES;
  float scale = (b == 1) ? inv_s : 1.f;
  short* WT = (b == 0) ? WqT : (b == 1) ? WkT : (b == 2) ? WvT : WeT;
  float* bias = (b == 0) ? bq : (b == 1) ? bk : (b == 2) ? bv : be;
  if (t < DIM) {
    float mean = stats[t] / M;
    float var = stats[DIM + t] / M - mean * mean;
    float a = gamma[t] * rsqrtf(var + 1e-5f);
    sab[t] = a;
    sbb[t] = beta[t] - mean * a;
  }
  __syncthreads();
  int d = t & 127, kg = t >> 7;
  int ct = d >> 4, lr = d & 15;
  int L = (ct >> 1) * 32 + lr * 2 + (ct & 1);
  float bacc = 0.f;
#pragma unroll
  for (int j = 0; j < 16; ++j) {
    int k = kg * 16 + j;
    float wv = W[k * DIM + L];
    WT[d * DIM + k] = f2bf(scale * sab[k] * wv);
    bacc += sbb[k] * wv;
  }
  red[kg][d] = bacc;
  __syncthreads();
  if (kg == 0) {
    float s = 0.f;
#pragma unroll
    for (int j = 0; j < 8; ++j) s += red[j][d];
    bias[d] = scale * s;
  }
}

// ---- fold BN2 into W1: parallel (16 blocks x 256 thr, LDS bias reduce) ----
__global__ __launch_bounds__(256) void fold_w1_kernel(
    const float* __restrict__ W1, const float* __restrict__ stats_h,
    const float* __restrict__ g2, const float* __restrict__ b2,
    short* __restrict__ W1F, float* __restrict__ bias1) {
  __shared__ float sab[DIM], sbb[DIM];
  __shared__ float red[16][17];
  int t = threadIdx.x;
  if (t < DIM) {
    float mean = stats_h[t] / (float)N_NODES;
    float var = stats_h[DIM + t] / (float)N_NODES - mean * mean;
    float a = g2[t] * rsqrtf(var + 1e-5f);
    sab[t] = a;
    sbb[t] = b2[t] - mean * a;
  }
  __syncthreads();
  int dl = t & 15, kg = t >> 4;
  int d = blockIdx.x * 16 + dl;
  float bacc = 0.f;
#pragma unroll
  for (int j = 0; j < 8; ++j) {
    int k = kg * 8 + j;
    float wv = W1[k * 256 + d];
    W1F[d * DIM + k] = f2bf(sab[k] * wv);
    bacc += sbb[k] * wv;
  }
  red[dl][kg] = bacc;
  __syncthreads();
  if (kg == 0) {
    float s = 0.f;
#pragma unroll
    for (int j = 0; j < 16; ++j) s += red[dl][j];
    bias1[d] = s;
  }
}

// ---- load A fragments (4 k-steps) for 16 rows at m0, fp32->bf16 ----
__device__ inline void load_a_frags(const float* __restrict__ X, long m0,
                                    int lr, int lg, bf16x8 a[4]) {
#pragma unroll
  for (int ks = 0; ks < 4; ++ks) {
    const float* p = X + (m0 + lr) * DIM + ks * 32 + lg * 8;
    float4 v0 = *reinterpret_cast<const float4*>(p);
    float4 v1 = *reinterpret_cast<const float4*>(p + 4);
    bf16x8 af;
    af[0] = f2bf(v0.x); af[1] = f2bf(v0.y); af[2] = f2bf(v0.z); af[3] = f2bf(v0.w);
    af[4] = f2bf(v1.x); af[5] = f2bf(v1.y); af[6] = f2bf(v1.z); af[7] = f2bf(v1.w);
    a[ks] = af;
  }
}

// ---------------- QKV via MFMA -> packed bf16 ----------------
__global__ __launch_bounds__(256) void qkv_mfma_kernel(
    const float* __restrict__ nf,
    const short* __restrict__ WqT, const short* __restrict__ WkT, const short* __restrict__ WvT,
    const float* __restrict__ bq, const float* __restrict__ bk, const float* __restrict__ bv,
    ushort* __restrict__ Qb, ushort* __restrict__ Kb, ushort* __restrict__ Vb) {
  int t = threadIdx.x;
  int w = t >> 6, l = t & 63;
  int lr = l & 15, lg = l >> 4;
  long m0 = (long)blockIdx.x * 64 + w * 16;
  if (m0 >= N_NODES) return;
  bf16x8 a[4];
  load_a_frags(nf, m0, lr, lg, a);
  const short* Ws[3] = {WqT, WkT, WvT};
  const float* bs[3] = {bq, bk, bv};
  ushort* Os[3] = {Qb, Kb, Vb};
#pragma unroll 1
  for (int m = 0; m < 3; ++m) {
    const short* WT = Ws[m];
    f32x4 acc[8];
#pragma unroll
    for (int ct = 0; ct < 8; ++ct) acc[ct] = (f32x4){0.f, 0.f, 0.f, 0.f};
#pragma unroll
    for (int ct = 0; ct < 8; ++ct) {
#pragma unroll
      for (int ks = 0; ks < 4; ++ks) {
        bf16x8 b = *reinterpret_cast<const bf16x8*>(WT + (ct * 16 + lr) * DIM + ks * 32 + lg * 8);
        acc[ct] = __builtin_amdgcn_mfma_f32_16x16x32_bf16(a[ks], b, acc[ct], 0, 0, 0);
      }
    }
    const float* bb = bs[m];
    ushort* O = Os[m];
#pragma unroll
    for (int h = 0; h < 4; ++h) {
      float b0 = bb[(2 * h) * 16 + lr];
      float b1 = bb[(2 * h + 1) * 16 + lr];
#pragma unroll
      for (int r = 0; r < 4; ++r) {
        uint u = pack_bf2(acc[2 * h][r] + b0, acc[2 * h + 1][r] + b1);
        *reinterpret_cast<uint*>(O + (m0 + lg * 4 + r) * DIM + h * 32 + lr * 2) = u;
      }
    }
  }
}

// ---------------- CSR scan + scatter (int2: src, e) ----------------
#define SCAN_T 1024
#define PER_T 49
__global__ __launch_bounds__(SCAN_T) void scan_kernel(
    const int* __restrict__ deg, int* __restrict__ row_start, int* __restrict__ cursor) {
  __shared__ int ps[SCAN_T];
  int t = threadIdx.x;
  int base = t * PER_T;
  int lsum = 0;
  int local[PER_T];
#pragma unroll
  for (int j = 0; j < PER_T; ++j) {
    int idx = base + j;
    int d = (idx < N_NODES) ? deg[idx] : 0;
    local[j] = lsum;
    lsum += d;
  }
  ps[t] = lsum;
  __syncthreads();
  for (int off = 1; off < SCAN_T; off <<= 1) {
    int v = (t >= off) ? ps[t - off] : 0;
    __syncthreads();
    ps[t] += v;
    __syncthreads();
  }
  int prefix = (t == 0) ? 0 : ps[t - 1];
#pragma unroll
  for (int j = 0; j < PER_T; ++j) {
    int idx = base + j;
    if (idx < N_NODES) {
      int v = prefix + local[j];
      row_start[idx] = v;
      cursor[idx] = v;
    }
  }
  if (t == SCAN_T - 1) row_start[N_NODES] = ps[SCAN_T - 1];
}

__global__ __launch_bounds__(256) void scatter_kernel(
    const int* __restrict__ src, const int* __restrict__ dst,
    int* __restrict__ cursor, int2* __restrict__ csr) {
  int i = blockIdx.x * 256 + threadIdx.x;
  int d = dst[i];
  int pos = atomicAdd(&cursor[d], 1);
  csr[pos] = make_int2(src[i], i);
}

// ------- edge score: bf16 ef input (L3-resident), simple persistent loop -------
#define ES_GRID 2048
__global__ __launch_bounds__(256) void edge_score_kernel(
    const ushort* __restrict__ efb,
    const int* __restrict__ src, const int* __restrict__ dst,
    const short* __restrict__ WeT, const float* __restrict__ be,
    const ushort* __restrict__ Qb, const ushort* __restrict__ Kb,
    float* __restrict__ s_out) {
  const int NT = N_EDGES / 64;
  int t = threadIdx.x;
  int w = t >> 6, l = t & 63;
  int lr = l & 15, lg = l >> 4;
  float ber[8];
#pragma unroll
  for (int ct = 0; ct < 8; ++ct) ber[ct] = be[ct * 16 + lr];

  for (int tile = blockIdx.x; tile < NT; tile += gridDim.x) {
    long m0 = (long)tile * 64 + w * 16;
    long eb = m0 + lg * 4;
    int4 s4 = *reinterpret_cast<const int4*>(src + eb);
    int4 d4 = *reinterpret_cast<const int4*>(dst + eb);
    int sn[4] = {s4.x, s4.y, s4.z, s4.w};
    int dn[4] = {d4.x, d4.y, d4.z, d4.w};
    // issue K/Q gathers
    uint Kg[4][4], Qg[4][4];
#pragma unroll
    for (int r = 0; r < 4; ++r) {
#pragma unroll
      for (int h = 0; h < 4; ++h) {
        Kg[r][h] = *reinterpret_cast<const uint*>(Kb + (long)sn[r] * DIM + h * 32 + lr * 2);
        Qg[r][h] = *reinterpret_cast<const uint*>(Qb + (long)dn[r] * DIM + h * 32 + lr * 2);
      }
    }
    // A-fragments: direct bf16 loads (no cvt) — efb is L3-resident
    bf16x8 a[4];
#pragma unroll
    for (int ks = 0; ks < 4; ++ks) {
      a[ks] = *reinterpret_cast<const bf16x8*>(efb + (m0 + lr) * DIM + ks * 32 + lg * 8);
    }
    // MFMA projection (hides gather latency)
    f32x4 acc[8];
#pragma unroll
    for (int ct = 0; ct < 8; ++ct) acc[ct] = (f32x4){0.f, 0.f, 0.f, 0.f};
#pragma unroll
    for (int ct = 0; ct < 8; ++ct) {
#pragma unroll
      for (int ks = 0; ks < 4; ++ks) {
        bf16x8 b = *reinterpret_cast<const bf16x8*>(WeT + (ct * 16 + lr) * DIM + ks * 32 + lg * 8);
        acc[ct] = __builtin_amdgcn_mfma_f32_16x16x32_bf16(a[ks], b, acc[ct], 0, 0, 0);
      }
    }
    // score + reduce + store
#pragma unroll
    for (int r = 0; r < 4; ++r) {
      float hs0, hs1, hs2, hs3;
      {
        float h0, h1, h2, h3;
#pragma unroll
        for (int h = 0; h < 4; ++h) {
          float k0 = bflo(Kg[r][h]), k1 = bfhi(Kg[r][h]);
          float q0 = bflo(Qg[r][h]), q1 = bfhi(Qg[r][h]);
          float pe0 = acc[2 * h][r] + ber[2 * h];
          float pe1 = acc[2 * h + 1][r] + ber[2 * h + 1];
          float v = fminf(fmaxf(k0 * q0, -5.f), 5.f) * pe0
                  + fminf(fmaxf(k1 * q1, -5.f), 5.f) * pe1;
          if (h == 0) h0 = v; else if (h == 1) h1 = v; else if (h == 2) h2 = v; else h3 = v;
        }
        hs0 = h0; hs1 = h1; hs2 = h2; hs3 = h3;
      }
#pragma unroll
      for (int m2 = 8; m2 >= 1; m2 >>= 1) {
        hs0 += __shfl_xor(hs0, m2);
        hs1 += __shfl_xor(hs1, m2);
        hs2 += __shfl_xor(hs2, m2);
        hs3 += __shfl_xor(hs3, m2);
      }
      if (lr < 4) {
        float myh = (lr == 0) ? hs0 : ((lr == 1) ? hs1 : ((lr == 2) ? hs2 : hs3));
        s_out[(eb + r) * 4 + lr] = __expf(fminf(fmaxf(myh, -5.f), 5.f));
      }
    }
  }
}

// ------- aggregate: one wave per dst node, 4-deep batched loads; bf16 output -------
__global__ __launch_bounds__(256) void aggregate_kernel(
    const int* __restrict__ row_start, const int2* __restrict__ csr,
    const float* __restrict__ s_arr, const ushort* __restrict__ Vb,
    ushort* __restrict__ haggb) {
  int t = threadIdx.x;
  int w = t >> 6, l = t & 63;
  int n = blockIdx.x * 4 + w;
  int r0 = row_start[n], r1 = row_start[n + 1];
  int h = l >> 4;
  float a0 = 0.f, a1 = 0.f, zacc = 0.f;
  int idx = r0;
  for (; idx + 4 <= r1; idx += 4) {
    int2 rec[4];
#pragma unroll
    for (int j = 0; j < 4; ++j) rec[j] = csr[idx + j];
    float sv[4]; uint uv[4];
#pragma unroll
    for (int j = 0; j < 4; ++j) {
      sv[j] = s_arr[(long)rec[j].y * 4 + h];
      uv[j] = *reinterpret_cast<const uint*>(Vb + (long)rec[j].x * DIM + l * 2);
    }
#pragma unroll
    for (int j = 0; j < 4; ++j) {
      a0 += sv[j] * bflo(uv[j]);
      a1 += sv[j] * bfhi(uv[j]);
      zacc += sv[j];
    }
  }
  for (; idx < r1; ++idx) {
    int2 ra = csr[idx];
    float sa = s_arr[(long)ra.y * 4 + h];
    uint ua = *reinterpret_cast<const uint*>(Vb + (long)ra.x * DIM + l * 2);
    a0 += sa * bflo(ua);
    a1 += sa * bfhi(ua);
    zacc += sa;
  }
  float inv = 1.f / (zacc + 1e-6f);
  *reinterpret_cast<uint*>(haggb + (long)n * DIM + l * 2) = pack_bf2(a0 * inv, a1 * inv);
}

// ---------------- attnout via MFMA: hres = h_in1 + hagg @ Ow + Ob; BN2 stats ----------------
__global__ __launch_bounds__(256) void attnout_mfma_kernel(
    const ushort* __restrict__ haggb, const short* __restrict__ OwT,
    const float* __restrict__ Ob, const float* __restrict__ h_in1,
    float* __restrict__ hres, float* __restrict__ stats2) {
  int t = threadIdx.x;
  int w = t >> 6, l = t & 63;
  int lr = l & 15, lg = l >> 4;
  long m0 = (long)blockIdx.x * 64 + w * 16;
  if (m0 >= N_NODES) return;
  bf16x8 a[4];
#pragma unroll
  for (int ks = 0; ks < 4; ++ks) {
    a[ks] = *reinterpret_cast<const bf16x8*>(haggb + (m0 + lr) * DIM + ks * 32 + lg * 8);
  }
  f32x4 acc[8];
#pragma unroll
  for (int ct = 0; ct < 8; ++ct) acc[ct] = (f32x4){0.f, 0.f, 0.f, 0.f};
#pragma unroll
  for (int ct = 0; ct < 8; ++ct) {
#pragma unroll
    for (int ks = 0; ks < 4; ++ks) {
      bf16x8 b = *reinterpret_cast<const bf16x8*>(OwT + (ct * 16 + lr) * DIM + ks * 32 + lg * 8);
      acc[ct] = __builtin_amdgcn_mfma_f32_16x16x32_bf16(a[ks], b, acc[ct], 0, 0, 0);
    }
  }
#pragma unroll
  for (int ct = 0; ct < 8; ++ct) {
    float ob = Ob[ct * 16 + lr];
    float ls = 0.f, lq = 0.f;
#pragma unroll
    for (int r = 0; r < 4; ++r) {
      long idx = (m0 + lg * 4 + r) * DIM + ct * 16 + lr;
      float hv = h_in1[idx] + acc[ct][r] + ob;
      hres[idx] = hv;
      ls += hv; lq += hv * hv;
    }
    ls += __shfl_xor(ls, 16); ls += __shfl_xor(ls, 32);
    lq += __shfl_xor(lq, 16); lq += __shfl_xor(lq, 32);
    if (lg == 0) {
      atomicAdd(&stats2[ct * 16 + lr], ls);
      atomicAdd(&stats2[DIM + ct * 16 + lr], lq);
    }
  }
}

// ---------------- MLP via MFMA: out = hres + silu(BN2(hres) @ W1) @ W2 ----------------
__global__ __launch_bounds__(256) void mlp_mfma_kernel(
    const float* __restrict__ hres, const short* __restrict__ W1F,
    const float* __restrict__ bias1, const short* __restrict__ W2T,
    float* __restrict__ out) {
  __shared__ short mid[64][264];  // padded: 2-way bank conflicts only
  int t = threadIdx.x;
  int w = t >> 6, l = t & 63;
  int lr = l & 15, lg = l >> 4;
  long m0 = (long)blockIdx.x * 64 + w * 16;
  if (m0 >= N_NODES) return;
  bf16x8 a1[4];
  load_a_frags(hres, m0, lr, lg, a1);
#pragma unroll
  for (int ct = 0; ct < 16; ++ct) {
    f32x4 acc = (f32x4){0.f, 0.f, 0.f, 0.f};
#pragma unroll
    for (int ks = 0; ks < 4; ++ks) {
      bf16x8 b = *reinterpret_cast<const bf16x8*>(W1F + (ct * 16 + lr) * DIM + ks * 32 + lg * 8);
      acc = __builtin_amdgcn_mfma_f32_16x16x32_bf16(a1[ks], b, acc, 0, 0, 0);
    }
    float bb = bias1[ct * 16 + lr];
#pragma unroll
    for (int r = 0; r < 4; ++r) {
      float x = acc[r] + bb;
      float sl = x / (1.f + __expf(-x));
      mid[w * 16 + lg * 4 + r][ct * 16 + lr] = f2bf(sl);
    }
  }
  bf16x8 a2[8];
#pragma unroll
  for (int ks = 0; ks < 8; ++ks) {
    a2[ks] = *reinterpret_cast<const bf16x8*>(&mid[w * 16 + lr][ks * 32 + lg * 8]);
  }
#pragma unroll
  for (int ct = 0; ct < 8; ++ct) {
    f32x4 acc = (f32x4){0.f, 0.f, 0.f, 0.f};
#pragma unroll
    for (int ks = 0; ks < 8; ++ks) {
      bf16x8 b = *reinterpret_cast<const bf16x8*>(W2T + (ct * 16 + lr) * 256 + ks * 32 + lg * 8);
      acc = __builtin_amdgcn_mfma_f32_16x16x32_bf16(a2[ks], b, acc, 0, 0, 0);
    }
#pragma unroll
    for (int r = 0; r < 4; ++r) {
      long idx = (m0 + lg * 4 + r) * DIM + ct * 16 + lr;
      out[idx] = hres[idx] + acc[r];
    }
  }
}

extern "C" void kernel_launch(void* const* d_in, const int* in_sizes, int n_in,
                              void* d_out, int out_size, void* d_ws, size_t ws_size,
                              hipStream_t stream) {
  const float* node_feats = (const float*)d_in[0];
  const float* edge_feats = (const float*)d_in[1];
  const int* src = (const int*)d_in[2];
  const int* dst = (const int*)d_in[3];
  const float* Wq = (const float*)d_in[4];
  const float* Wk = (const float*)d_in[5];
  const float* Wv = (const float*)d_in[6];
  const float* We = (const float*)d_in[7];
  const float* Ow = (const float*)d_in[8];
  const float* Ob = (const float*)d_in[9];
  const float* g1n = (const float*)d_in[10];
  const float* b1n = (const float*)d_in[11];
  const float* g1e = (const float*)d_in[12];
  const float* b1e = (const float*)d_in[13];
  const float* g2 = (const float*)d_in[14];
  const float* b2 = (const float*)d_in[15];
  const float* W1 = (const float*)d_in[16];
  const float* W2 = (const float*)d_in[17];
  float* out = (float*)d_out;
  float* w = (float*)d_ws;

  float* stats_n = w + 0;
  float* stats_e = w + 256;
  float* stats_h = w + 512;
  float* bq = w + 1536;
  float* bk = w + 1664;
  float* bv = w + 1792;
  float* be = w + 1920;
  short* WqT = (short*)(w + 2048);    // 128x128 bf16 = 8192 floats
  short* WkT = (short*)(w + 10240);
  short* WvT = (short*)(w + 18432);
  short* WeT = (short*)(w + 26624);
  short* OwT = (short*)(w + 34816);   // 8192 floats
  short* W1F = (short*)(w + 43008);   // 256x128 bf16 = 16384 floats
  short* W2T = (short*)(w + 59392);   // 128x256 bf16 = 16384 floats
  float* bias1 = w + 75776;           // 256
  ushort* Qb = (ushort*)(w + 76032);  // N*128 bf16 = 3.2M floats
  ushort* Kb = (ushort*)(w + 3276032);
  ushort* Vb = (ushort*)(w + 6476032);
  float* s_arr = w + 9676032;         // E*4 floats (edge-id order)
  int* deg = (int*)(w + 12876032);
  int* row_start = deg + 50048;
  int* cursor = row_start + 50064;
  int2* csr = (int2*)(cursor + 50048);        // 1.6M int2 = 3.2M ints
  ushort* efb = (ushort*)(w + 16226192);      // E*128 bf16 = 51.2M floats
  ushort* haggb = (ushort*)(w + 76032);       // overlays Qb (dead after edge_score)

  const float inv_s = 0.17677669529663687f;  // 1/sqrt(32), folded into K

  hipMemsetAsync(w, 0, 768 * sizeof(float), stream);
  hipMemsetAsync(deg, 0, 50000 * sizeof(int), stream);

  stats_all_kernel<<<2560, 256, 0, stream>>>(
      node_feats, edge_feats, dst, stats_n, stats_e, deg, efb);
  fold6_kernel<<<6, 1024, 0, stream>>>(Wq, Wk, Wv, We, Ow, W2, stats_n, stats_e,
                                       g1n, b1n, g1e, b1e, inv_s,
                                       WqT, WkT, WvT, WeT, OwT, W2T, bq, bk, bv, be);
  scan_kernel<<<1, SCAN_T, 0, stream>>>(deg, row_start, cursor);
  scatter_kernel<<<N_EDGES / 256, 256, 0, stream>>>(src, dst, cursor, csr);

  qkv_mfma_kernel<<<(N_NODES + 63) / 64, 256, 0, stream>>>(
      node_feats, WqT, WkT, WvT, bq, bk, bv, Qb, Kb, Vb);
  edge_score_kernel<<<ES_GRID, 256, 0, stream>>>(
      efb, src, dst, WeT, be, Qb, Kb, s_arr);
  aggregate_kernel<<<N_NODES / 4, 256, 0, stream>>>(row_start, csr, s_arr, Vb, haggb);
  attnout_mfma_kernel<<<(N_NODES + 63) / 64, 256, 0, stream>>>(
      haggb, OwT, Ob, node_feats, out, stats_h);
  fold_w1_kernel<<<16, 256, 0, stream>>>(W1, stats_h, g2, b2, W1F, bias1);
  mlp_mfma_kernel<<<(N_NODES + 63) / 64, 256, 0, stream>>>(out, W1F, bias1, W2T, out);
}

// Round 12
// 732.494 us; speedup vs baseline: 1.1488x; 1.1129x over previous
//
#include <hip/hip_runtime.h>
#include <hip/hip_bf16.h>
#include <math.h>

#define N_NODES 50000
#define N_EDGES 800000
#define DIM 128
#define NH 4

typedef __attribute__((ext_vector_type(8))) short bf16x8;
typedef __attribute__((ext_vector_type(4))) float f32x4;
typedef unsigned int uint;
typedef unsigned short ushort;

__device__ inline short f2bf(float f) {
  __hip_bfloat16 h = __float2bfloat16(f);
  return __builtin_bit_cast(short, h);
}
__device__ inline uint pack_bf2(float lo, float hi) {
  return (uint)(ushort)f2bf(lo) | ((uint)(ushort)f2bf(hi) << 16);
}
__device__ inline float bflo(uint u) { return __builtin_bit_cast(float, u << 16); }
__device__ inline float bfhi(uint u) { return __builtin_bit_cast(float, u & 0xffff0000u); }

// ---- fused stats: blocks <512 node stats; blocks >=512 edge stats + hist + bf16 stage ----
__global__ __launch_bounds__(256) void stats_all_kernel(
    const float* __restrict__ nf, const float* __restrict__ ef,
    const int* __restrict__ dst,
    float* __restrict__ stats_n, float* __restrict__ stats_e,
    int* __restrict__ deg, ushort* __restrict__ efb) {
  __shared__ float s_sum[DIM];
  __shared__ float s_sq[DIM];
  int t = threadIdx.x;
  if (t < DIM) { s_sum[t] = 0.f; s_sq[t] = 0.f; }
  __syncthreads();
  int c4 = (t & 31) * 4;
  int rg = t >> 5;
  float sum0=0,sum1=0,sum2=0,sum3=0, sq0=0,sq1=0,sq2=0,sq3=0;
  if (blockIdx.x < 512) {
    for (long row = (long)blockIdx.x * 8 + rg; row < N_NODES; row += 512L * 8) {
      float4 v = *reinterpret_cast<const float4*>(nf + row * DIM + c4);
      sum0 += v.x; sq0 += v.x * v.x;
      sum1 += v.y; sq1 += v.y * v.y;
      sum2 += v.z; sq2 += v.z * v.z;
      sum3 += v.w; sq3 += v.w * v.w;
    }
    atomicAdd(&s_sum[c4 + 0], sum0); atomicAdd(&s_sq[c4 + 0], sq0);
    atomicAdd(&s_sum[c4 + 1], sum1); atomicAdd(&s_sq[c4 + 1], sq1);
    atomicAdd(&s_sum[c4 + 2], sum2); atomicAdd(&s_sq[c4 + 2], sq2);
    atomicAdd(&s_sum[c4 + 3], sum3); atomicAdd(&s_sq[c4 + 3], sq3);
    __syncthreads();
    if (t < DIM) {
      atomicAdd(&stats_n[t], s_sum[t]);
      atomicAdd(&stats_n[DIM + t], s_sq[t]);
    }
  } else {
    long bid2 = blockIdx.x - 512;  // 0..2047
    for (long i = bid2 * 256 + t; i < N_EDGES; i += 2048L * 256) {
      atomicAdd(&deg[dst[i]], 1);
    }
    for (long row = bid2 * 8 + rg; row < N_EDGES; row += 2048L * 8) {
      float4 v = *reinterpret_cast<const float4*>(ef + row * DIM + c4);
      sum0 += v.x; sq0 += v.x * v.x;
      sum1 += v.y; sq1 += v.y * v.y;
      sum2 += v.z; sq2 += v.z * v.z;
      sum3 += v.w; sq3 += v.w * v.w;
      uint2 p;
      p.x = pack_bf2(v.x, v.y);
      p.y = pack_bf2(v.z, v.w);
      *reinterpret_cast<uint2*>(efb + row * DIM + c4) = p;
    }
    atomicAdd(&s_sum[c4 + 0], sum0); atomicAdd(&s_sq[c4 + 0], sq0);
    atomicAdd(&s_sum[c4 + 1], sum1); atomicAdd(&s_sq[c4 + 1], sq1);
    atomicAdd(&s_sum[c4 + 2], sum2); atomicAdd(&s_sq[c4 + 2], sq2);
    atomicAdd(&s_sum[c4 + 3], sum3); atomicAdd(&s_sq[c4 + 3], sq3);
    __syncthreads();
    if (t < DIM) {
      atomicAdd(&stats_e[t], s_sum[t]);
      atomicAdd(&stats_e[DIM + t], s_sq[t]);
    }
  }
}

// ---- fold7: blocks 0-3 BN-folded Wq/Wk/Wv/We; 4 OwT; 5 W2T; 6 CSR scan ----
#define SCAN_T 1024
#define PER_T 49
__global__ __launch_bounds__(1024) void fold7_kernel(
    const float* __restrict__ Wq, const float* __restrict__ Wk,
    const float* __restrict__ Wv, const float* __restrict__ We,
    const float* __restrict__ Ow, const float* __restrict__ W2,
    const float* __restrict__ stats_n, const float* __restrict__ stats_e,
    const float* __restrict__ g1n, const float* __restrict__ b1n,
    const float* __restrict__ g1e, const float* __restrict__ b1e, float inv_s,
    short* __restrict__ WqT, short* __restrict__ WkT,
    short* __restrict__ WvT, short* __restrict__ WeT,
    short* __restrict__ OwT, short* __restrict__ W2T,
    float* __restrict__ bq, float* __restrict__ bk,
    float* __restrict__ bv, float* __restrict__ be,
    const int* __restrict__ deg, int* __restrict__ row_start,
    int* __restrict__ cursor) {
  int b = blockIdx.x;
  int t = threadIdx.x;
  if (b == 6) {  // ---- CSR prefix scan ----
    __shared__ int ps[SCAN_T];
    int base = t * PER_T;
    int lsum = 0;
    int local[PER_T];
#pragma unroll
    for (int j = 0; j < PER_T; ++j) {
      int idx = base + j;
      int d = (idx < N_NODES) ? deg[idx] : 0;
      local[j] = lsum;
      lsum += d;
    }
    ps[t] = lsum;
    __syncthreads();
    for (int off = 1; off < SCAN_T; off <<= 1) {
      int v = (t >= off) ? ps[t - off] : 0;
      __syncthreads();
      ps[t] += v;
      __syncthreads();
    }
    int prefix = (t == 0) ? 0 : ps[t - 1];
#pragma unroll
    for (int j = 0; j < PER_T; ++j) {
      int idx = base + j;
      if (idx < N_NODES) {
        int v = prefix + local[j];
        row_start[idx] = v;
        cursor[idx] = v;
      }
    }
    if (t == SCAN_T - 1) row_start[N_NODES] = ps[SCAN_T - 1];
    return;
  }
  if (b == 4) {
    int d = t & 127, kg = t >> 7;
#pragma unroll
    for (int j = 0; j < 16; ++j) {
      int k = kg * 16 + j;
      OwT[d * DIM + k] = f2bf(Ow[k * DIM + d]);
    }
    return;
  }
  if (b == 5) {
    int d = t & 127, kg = t >> 7;
#pragma unroll
    for (int j = 0; j < 32; ++j) {
      int k = kg * 32 + j;
      W2T[d * 256 + k] = f2bf(W2[k * DIM + d]);
    }
    return;
  }
  __shared__ float red[8][DIM];
  __shared__ float sab[DIM], sbb[DIM];
  const float* W = (b == 0) ? Wq : (b == 1) ? Wk : (b == 2) ? Wv : We;
  const float* stats = (b == 3) ? stats_e : stats_n;
  const float* gamma = (b == 3) ? g1e : g1n;
  const float* beta  = (b == 3) ? b1e : b1n;
  float M            = (b == 3) ? (float)N_EDGES : (float)N_NODES;
  float scale = (b == 1) ? inv_s : 1.f;
  short* WT = (b == 0) ? WqT : (b == 1) ? WkT : (b == 2) ? WvT : WeT;
  float* bias = (b == 0) ? bq : (b == 1) ? bk : (b == 2) ? bv : be;
  if (t < DIM) {
    float mean = stats[t] / M;
    float var = stats[DIM + t] / M - mean * mean;
    float a = gamma[t] * rsqrtf(var + 1e-5f);
    sab[t] = a;
    sbb[t] = beta[t] - mean * a;
  }
  __syncthreads();
  int d = t & 127, kg = t >> 7;
  int ct = d >> 4, lr = d & 15;
  int L = (ct >> 1) * 32 + lr * 2 + (ct & 1);
  float bacc = 0.f;
#pragma unroll
  for (int j = 0; j < 16; ++j) {
    int k = kg * 16 + j;
    float wv = W[k * DIM + L];
    WT[d * DIM + k] = f2bf(scale * sab[k] * wv);
    bacc += sbb[k] * wv;
  }
  red[kg][d] = bacc;
  __syncthreads();
  if (kg == 0) {
    float s = 0.f;
#pragma unroll
    for (int j = 0; j < 8; ++j) s += red[j][d];
    bias[d] = scale * s;
  }
}

// ---- fold BN2 into W1: parallel (16 blocks x 256 thr, LDS bias reduce) ----
__global__ __launch_bounds__(256) void fold_w1_kernel(
    const float* __restrict__ W1, const float* __restrict__ stats_h,
    const float* __restrict__ g2, const float* __restrict__ b2,
    short* __restrict__ W1F, float* __restrict__ bias1) {
  __shared__ float sab[DIM], sbb[DIM];
  __shared__ float red[16][17];
  int t = threadIdx.x;
  if (t < DIM) {
    float mean = stats_h[t] / (float)N_NODES;
    float var = stats_h[DIM + t] / (float)N_NODES - mean * mean;
    float a = g2[t] * rsqrtf(var + 1e-5f);
    sab[t] = a;
    sbb[t] = b2[t] - mean * a;
  }
  __syncthreads();
  int dl = t & 15, kg = t >> 4;
  int d = blockIdx.x * 16 + dl;
  float bacc = 0.f;
#pragma unroll
  for (int j = 0; j < 8; ++j) {
    int k = kg * 8 + j;
    float wv = W1[k * 256 + d];
    W1F[d * DIM + k] = f2bf(sab[k] * wv);
    bacc += sbb[k] * wv;
  }
  red[dl][kg] = bacc;
  __syncthreads();
  if (kg == 0) {
    float s = 0.f;
#pragma unroll
    for (int j = 0; j < 16; ++j) s += red[dl][j];
    bias1[d] = s;
  }
}

// ---- load A fragments (4 k-steps) for 16 rows at m0, fp32->bf16 ----
__device__ inline void load_a_frags(const float* __restrict__ X, long m0,
                                    int lr, int lg, bf16x8 a[4]) {
#pragma unroll
  for (int ks = 0; ks < 4; ++ks) {
    const float* p = X + (m0 + lr) * DIM + ks * 32 + lg * 8;
    float4 v0 = *reinterpret_cast<const float4*>(p);
    float4 v1 = *reinterpret_cast<const float4*>(p + 4);
    bf16x8 af;
    af[0] = f2bf(v0.x); af[1] = f2bf(v0.y); af[2] = f2bf(v0.z); af[3] = f2bf(v0.w);
    af[4] = f2bf(v1.x); af[5] = f2bf(v1.y); af[6] = f2bf(v1.z); af[7] = f2bf(v1.w);
    a[ks] = af;
  }
}

// ---- fused scatter + QKV: blocks [0,782) QKV-MFMA; blocks [782, 3907) scatter ----
#define QKV_BLOCKS 782  // ceil(50000/64)
__global__ __launch_bounds__(256) void scatter_qkv_kernel(
    const float* __restrict__ nf,
    const short* __restrict__ WqT, const short* __restrict__ WkT, const short* __restrict__ WvT,
    const float* __restrict__ bq, const float* __restrict__ bk, const float* __restrict__ bv,
    ushort* __restrict__ Qb, ushort* __restrict__ Kb, ushort* __restrict__ Vb,
    const int* __restrict__ src, const int* __restrict__ dst,
    int* __restrict__ cursor, int2* __restrict__ csr) {
  int t = threadIdx.x;
  if (blockIdx.x >= QKV_BLOCKS) {
    // ---- scatter ----
    int i = (blockIdx.x - QKV_BLOCKS) * 256 + t;
    int d = dst[i];
    int pos = atomicAdd(&cursor[d], 1);
    csr[pos] = make_int2(src[i], i);
    return;
  }
  int w = t >> 6, l = t & 63;
  int lr = l & 15, lg = l >> 4;
  long m0 = (long)blockIdx.x * 64 + w * 16;
  if (m0 >= N_NODES) return;
  bf16x8 a[4];
  load_a_frags(nf, m0, lr, lg, a);
  const short* Ws[3] = {WqT, WkT, WvT};
  const float* bs[3] = {bq, bk, bv};
  ushort* Os[3] = {Qb, Kb, Vb};
#pragma unroll 1
  for (int m = 0; m < 3; ++m) {
    const short* WT = Ws[m];
    f32x4 acc[8];
#pragma unroll
    for (int ct = 0; ct < 8; ++ct) acc[ct] = (f32x4){0.f, 0.f, 0.f, 0.f};
#pragma unroll
    for (int ct = 0; ct < 8; ++ct) {
#pragma unroll
      for (int ks = 0; ks < 4; ++ks) {
        bf16x8 b = *reinterpret_cast<const bf16x8*>(WT + (ct * 16 + lr) * DIM + ks * 32 + lg * 8);
        acc[ct] = __builtin_amdgcn_mfma_f32_16x16x32_bf16(a[ks], b, acc[ct], 0, 0, 0);
      }
    }
    const float* bb = bs[m];
    ushort* O = Os[m];
#pragma unroll
    for (int h = 0; h < 4; ++h) {
      float b0 = bb[(2 * h) * 16 + lr];
      float b1 = bb[(2 * h + 1) * 16 + lr];
#pragma unroll
      for (int r = 0; r < 4; ++r) {
        uint u = pack_bf2(acc[2 * h][r] + b0, acc[2 * h + 1][r] + b1);
        *reinterpret_cast<uint*>(O + (m0 + lg * 4 + r) * DIM + h * 32 + lr * 2) = u;
      }
    }
  }
}

// ------- edge score: bf16 ef (nontemporal), setprio around MFMA -------
#define ES_GRID 2048
__global__ __launch_bounds__(256) void edge_score_kernel(
    const ushort* __restrict__ efb,
    const int* __restrict__ src, const int* __restrict__ dst,
    const short* __restrict__ WeT, const float* __restrict__ be,
    const ushort* __restrict__ Qb, const ushort* __restrict__ Kb,
    float* __restrict__ s_out) {
  const int NT = N_EDGES / 64;
  int t = threadIdx.x;
  int w = t >> 6, l = t & 63;
  int lr = l & 15, lg = l >> 4;
  float ber[8];
#pragma unroll
  for (int ct = 0; ct < 8; ++ct) ber[ct] = be[ct * 16 + lr];

  for (int tile = blockIdx.x; tile < NT; tile += gridDim.x) {
    long m0 = (long)tile * 64 + w * 16;
    long eb = m0 + lg * 4;
    int4 s4 = *reinterpret_cast<const int4*>(src + eb);
    int4 d4 = *reinterpret_cast<const int4*>(dst + eb);
    int sn[4] = {s4.x, s4.y, s4.z, s4.w};
    int dn[4] = {d4.x, d4.y, d4.z, d4.w};
    uint Kg[4][4], Qg[4][4];
#pragma unroll
    for (int r = 0; r < 4; ++r) {
#pragma unroll
      for (int h = 0; h < 4; ++h) {
        Kg[r][h] = *reinterpret_cast<const uint*>(Kb + (long)sn[r] * DIM + h * 32 + lr * 2);
        Qg[r][h] = *reinterpret_cast<const uint*>(Qb + (long)dn[r] * DIM + h * 32 + lr * 2);
      }
    }
    // A-fragments: nontemporal bf16 loads (don't evict Q/K from L3)
    bf16x8 a[4];
#pragma unroll
    for (int ks = 0; ks < 4; ++ks) {
      a[ks] = __builtin_nontemporal_load(
          reinterpret_cast<const bf16x8*>(efb + (m0 + lr) * DIM + ks * 32 + lg * 8));
    }
    f32x4 acc[8];
#pragma unroll
    for (int ct = 0; ct < 8; ++ct) acc[ct] = (f32x4){0.f, 0.f, 0.f, 0.f};
    __builtin_amdgcn_s_setprio(1);
#pragma unroll
    for (int ct = 0; ct < 8; ++ct) {
#pragma unroll
      for (int ks = 0; ks < 4; ++ks) {
        bf16x8 b = *reinterpret_cast<const bf16x8*>(WeT + (ct * 16 + lr) * DIM + ks * 32 + lg * 8);
        acc[ct] = __builtin_amdgcn_mfma_f32_16x16x32_bf16(a[ks], b, acc[ct], 0, 0, 0);
      }
    }
    __builtin_amdgcn_s_setprio(0);
#pragma unroll
    for (int r = 0; r < 4; ++r) {
      float hs0, hs1, hs2, hs3;
      {
        float h0, h1, h2, h3;
#pragma unroll
        for (int h = 0; h < 4; ++h) {
          float k0 = bflo(Kg[r][h]), k1 = bfhi(Kg[r][h]);
          float q0 = bflo(Qg[r][h]), q1 = bfhi(Qg[r][h]);
          float pe0 = acc[2 * h][r] + ber[2 * h];
          float pe1 = acc[2 * h + 1][r] + ber[2 * h + 1];
          float v = fminf(fmaxf(k0 * q0, -5.f), 5.f) * pe0
                  + fminf(fmaxf(k1 * q1, -5.f), 5.f) * pe1;
          if (h == 0) h0 = v; else if (h == 1) h1 = v; else if (h == 2) h2 = v; else h3 = v;
        }
        hs0 = h0; hs1 = h1; hs2 = h2; hs3 = h3;
      }
#pragma unroll
      for (int m2 = 8; m2 >= 1; m2 >>= 1) {
        hs0 += __shfl_xor(hs0, m2);
        hs1 += __shfl_xor(hs1, m2);
        hs2 += __shfl_xor(hs2, m2);
        hs3 += __shfl_xor(hs3, m2);
      }
      if (lr < 4) {
        float myh = (lr == 0) ? hs0 : ((lr == 1) ? hs1 : ((lr == 2) ? hs2 : hs3));
        s_out[(eb + r) * 4 + lr] = __expf(fminf(fmaxf(myh, -5.f), 5.f));
      }
    }
  }
}

// ------- aggregate: one wave per dst node, 4-deep batched loads; bf16 output -------
__global__ __launch_bounds__(256) void aggregate_kernel(
    const int* __restrict__ row_start, const int2* __restrict__ csr,
    const float* __restrict__ s_arr, const ushort* __restrict__ Vb,
    ushort* __restrict__ haggb) {
  int t = threadIdx.x;
  int w = t >> 6, l = t & 63;
  int n = blockIdx.x * 4 + w;
  int r0 = row_start[n], r1 = row_start[n + 1];
  int h = l >> 4;
  float a0 = 0.f, a1 = 0.f, zacc = 0.f;
  int idx = r0;
  for (; idx + 4 <= r1; idx += 4) {
    int2 rec[4];
#pragma unroll
    for (int j = 0; j < 4; ++j) rec[j] = csr[idx + j];
    float sv[4]; uint uv[4];
#pragma unroll
    for (int j = 0; j < 4; ++j) {
      sv[j] = s_arr[(long)rec[j].y * 4 + h];
      uv[j] = *reinterpret_cast<const uint*>(Vb + (long)rec[j].x * DIM + l * 2);
    }
#pragma unroll
    for (int j = 0; j < 4; ++j) {
      a0 += sv[j] * bflo(uv[j]);
      a1 += sv[j] * bfhi(uv[j]);
      zacc += sv[j];
    }
  }
  for (; idx < r1; ++idx) {
    int2 ra = csr[idx];
    float sa = s_arr[(long)ra.y * 4 + h];
    uint ua = *reinterpret_cast<const uint*>(Vb + (long)ra.x * DIM + l * 2);
    a0 += sa * bflo(ua);
    a1 += sa * bfhi(ua);
    zacc += sa;
  }
  float inv = 1.f / (zacc + 1e-6f);
  *reinterpret_cast<uint*>(haggb + (long)n * DIM + l * 2) = pack_bf2(a0 * inv, a1 * inv);
}

// ---------------- attnout via MFMA: hres = h_in1 + hagg @ Ow + Ob; BN2 stats ----------------
__global__ __launch_bounds__(256) void attnout_mfma_kernel(
    const ushort* __restrict__ haggb, const short* __restrict__ OwT,
    const float* __restrict__ Ob, const float* __restrict__ h_in1,
    float* __restrict__ hres, float* __restrict__ stats2) {
  int t = threadIdx.x;
  int w = t >> 6, l = t & 63;
  int lr = l & 15, lg = l >> 4;
  long m0 = (long)blockIdx.x * 64 + w * 16;
  if (m0 >= N_NODES) return;
  bf16x8 a[4];
#pragma unroll
  for (int ks = 0; ks < 4; ++ks) {
    a[ks] = *reinterpret_cast<const bf16x8*>(haggb + (m0 + lr) * DIM + ks * 32 + lg * 8);
  }
  f32x4 acc[8];
#pragma unroll
  for (int ct = 0; ct < 8; ++ct) acc[ct] = (f32x4){0.f, 0.f, 0.f, 0.f};
#pragma unroll
  for (int ct = 0; ct < 8; ++ct) {
#pragma unroll
    for (int ks = 0; ks < 4; ++ks) {
      bf16x8 b = *reinterpret_cast<const bf16x8*>(OwT + (ct * 16 + lr) * DIM + ks * 32 + lg * 8);
      acc[ct] = __builtin_amdgcn_mfma_f32_16x16x32_bf16(a[ks], b, acc[ct], 0, 0, 0);
    }
  }
#pragma unroll
  for (int ct = 0; ct < 8; ++ct) {
    float ob = Ob[ct * 16 + lr];
    float ls = 0.f, lq = 0.f;
#pragma unroll
    for (int r = 0; r < 4; ++r) {
      long idx = (m0 + lg * 4 + r) * DIM + ct * 16 + lr;
      float hv = h_in1[idx] + acc[ct][r] + ob;
      hres[idx] = hv;
      ls += hv; lq += hv * hv;
    }
    ls += __shfl_xor(ls, 16); ls += __shfl_xor(ls, 32);
    lq += __shfl_xor(lq, 16); lq += __shfl_xor(lq, 32);
    if (lg == 0) {
      atomicAdd(&stats2[ct * 16 + lr], ls);
      atomicAdd(&stats2[DIM + ct * 16 + lr], lq);
    }
  }
}

// ---------------- MLP via MFMA: out = hres + silu(BN2(hres) @ W1) @ W2 ----------------
__global__ __launch_bounds__(256) void mlp_mfma_kernel(
    const float* __restrict__ hres, const short* __restrict__ W1F,
    const float* __restrict__ bias1, const short* __restrict__ W2T,
    float* __restrict__ out) {
  __shared__ short mid[64][264];  // padded: 2-way bank conflicts only
  int t = threadIdx.x;
  int w = t >> 6, l = t & 63;
  int lr = l & 15, lg = l >> 4;
  long m0 = (long)blockIdx.x * 64 + w * 16;
  if (m0 >= N_NODES) return;
  bf16x8 a1[4];
  load_a_frags(hres, m0, lr, lg, a1);
#pragma unroll
  for (int ct = 0; ct < 16; ++ct) {
    f32x4 acc = (f32x4){0.f, 0.f, 0.f, 0.f};
#pragma unroll
    for (int ks = 0; ks < 4; ++ks) {
      bf16x8 b = *reinterpret_cast<const bf16x8*>(W1F + (ct * 16 + lr) * DIM + ks * 32 + lg * 8);
      acc = __builtin_amdgcn_mfma_f32_16x16x32_bf16(a1[ks], b, acc, 0, 0, 0);
    }
    float bb = bias1[ct * 16 + lr];
#pragma unroll
    for (int r = 0; r < 4; ++r) {
      float x = acc[r] + bb;
      float sl = x / (1.f + __expf(-x));
      mid[w * 16 + lg * 4 + r][ct * 16 + lr] = f2bf(sl);
    }
  }
  bf16x8 a2[8];
#pragma unroll
  for (int ks = 0; ks < 8; ++ks) {
    a2[ks] = *reinterpret_cast<const bf16x8*>(&mid[w * 16 + lr][ks * 32 + lg * 8]);
  }
#pragma unroll
  for (int ct = 0; ct < 8; ++ct) {
    f32x4 acc = (f32x4){0.f, 0.f, 0.f, 0.f};
#pragma unroll
    for (int ks = 0; ks < 8; ++ks) {
      bf16x8 b = *reinterpret_cast<const bf16x8*>(W2T + (ct * 16 + lr) * 256 + ks * 32 + lg * 8);
      acc = __builtin_amdgcn_mfma_f32_16x16x32_bf16(a2[ks], b, acc, 0, 0, 0);
    }
#pragma unroll
    for (int r = 0; r < 4; ++r) {
      long idx = (m0 + lg * 4 + r) * DIM + ct * 16 + lr;
      out[idx] = hres[idx] + acc[r];
    }
  }
}

extern "C" void kernel_launch(void* const* d_in, const int* in_sizes, int n_in,
                              void* d_out, int out_size, void* d_ws, size_t ws_size,
                              hipStream_t stream) {
  const float* node_feats = (const float*)d_in[0];
  const float* edge_feats = (const float*)d_in[1];
  const int* src = (const int*)d_in[2];
  const int* dst = (const int*)d_in[3];
  const float* Wq = (const float*)d_in[4];
  const float* Wk = (const float*)d_in[5];
  const float* Wv = (const float*)d_in[6];
  const float* We = (const float*)d_in[7];
  const float* Ow = (const float*)d_in[8];
  const float* Ob = (const float*)d_in[9];
  const float* g1n = (const float*)d_in[10];
  const float* b1n = (const float*)d_in[11];
  const float* g1e = (const float*)d_in[12];
  const float* b1e = (const float*)d_in[13];
  const float* g2 = (const float*)d_in[14];
  const float* b2 = (const float*)d_in[15];
  const float* W1 = (const float*)d_in[16];
  const float* W2 = (const float*)d_in[17];
  float* out = (float*)d_out;
  float* w = (float*)d_ws;

  float* stats_n = w + 0;
  float* stats_e = w + 256;
  float* stats_h = w + 512;
  float* bq = w + 1536;
  float* bk = w + 1664;
  float* bv = w + 1792;
  float* be = w + 1920;
  short* WqT = (short*)(w + 2048);    // 128x128 bf16 = 8192 floats
  short* WkT = (short*)(w + 10240);
  short* WvT = (short*)(w + 18432);
  short* WeT = (short*)(w + 26624);
  short* OwT = (short*)(w + 34816);   // 8192 floats
  short* W1F = (short*)(w + 43008);   // 256x128 bf16 = 16384 floats
  short* W2T = (short*)(w + 59392);   // 128x256 bf16 = 16384 floats
  float* bias1 = w + 75776;           // 256
  ushort* Qb = (ushort*)(w + 76032);  // N*128 bf16 = 3.2M floats
  ushort* Kb = (ushort*)(w + 3276032);
  ushort* Vb = (ushort*)(w + 6476032);
  float* s_arr = w + 9676032;         // E*4 floats (edge-id order)
  int* deg = (int*)(w + 12876032);
  int* row_start = deg + 50048;
  int* cursor = row_start + 50064;
  int2* csr = (int2*)(cursor + 50048);        // 1.6M int2 = 3.2M ints
  ushort* efb = (ushort*)(w + 16226192);      // E*128 bf16 = 51.2M floats
  ushort* haggb = (ushort*)(w + 76032);       // overlays Qb (dead after edge_score)

  const float inv_s = 0.17677669529663687f;  // 1/sqrt(32), folded into K

  hipMemsetAsync(w, 0, 768 * sizeof(float), stream);
  hipMemsetAsync(deg, 0, 50000 * sizeof(int), stream);

  stats_all_kernel<<<2560, 256, 0, stream>>>(
      node_feats, edge_feats, dst, stats_n, stats_e, deg, efb);
  fold7_kernel<<<7, 1024, 0, stream>>>(Wq, Wk, Wv, We, Ow, W2, stats_n, stats_e,
                                       g1n, b1n, g1e, b1e, inv_s,
                                       WqT, WkT, WvT, WeT, OwT, W2T, bq, bk, bv, be,
                                       deg, row_start, cursor);
  scatter_qkv_kernel<<<QKV_BLOCKS + N_EDGES / 256, 256, 0, stream>>>(
      node_feats, WqT, WkT, WvT, bq, bk, bv, Qb, Kb, Vb, src, dst, cursor, csr);
  edge_score_kernel<<<ES_GRID, 256, 0, stream>>>(
      efb, src, dst, WeT, be, Qb, Kb, s_arr);
  aggregate_kernel<<<N_NODES / 4, 256, 0, stream>>>(row_start, csr, s_arr, Vb, haggb);
  attnout_mfma_kernel<<<(N_NODES + 63) / 64, 256, 0, stream>>>(
      haggb, OwT, Ob, node_feats, out, stats_h);
  fold_w1_kernel<<<16, 256, 0, stream>>>(W1, stats_h, g2, b2, W1F, bias1);
  mlp_mfma_kernel<<<(N_NODES + 63) / 64, 256, 0, stream>>>(out, W1F, bias1, W2T, out);
}

// Round 13
// 715.506 us; speedup vs baseline: 1.1761x; 1.0237x over previous
//
#include <hip/hip_runtime.h>
#include <hip/hip_bf16.h>
#include <math.h>

#define N_NODES 50000
#define N_EDGES 800000
#define DIM 128
#define NH 4

typedef __attribute__((ext_vector_type(8))) short bf16x8;
typedef __attribute__((ext_vector_type(4))) float f32x4;
typedef unsigned int uint;
typedef unsigned short ushort;

__device__ inline short f2bf(float f) {
  __hip_bfloat16 h = __float2bfloat16(f);
  return __builtin_bit_cast(short, h);
}
__device__ inline uint pack_bf2(float lo, float hi) {
  return (uint)(ushort)f2bf(lo) | ((uint)(ushort)f2bf(hi) << 16);
}
__device__ inline float bflo(uint u) { return __builtin_bit_cast(float, u << 16); }
__device__ inline float bfhi(uint u) { return __builtin_bit_cast(float, u & 0xffff0000u); }

// ---- fused stats: blocks <512 node stats; blocks >=512 edge stats + hist + bf16 stage ----
__global__ __launch_bounds__(256) void stats_all_kernel(
    const float* __restrict__ nf, const float* __restrict__ ef,
    const int* __restrict__ dst,
    float* __restrict__ stats_n, float* __restrict__ stats_e,
    int* __restrict__ deg, ushort* __restrict__ efb) {
  __shared__ float s_sum[DIM];
  __shared__ float s_sq[DIM];
  int t = threadIdx.x;
  if (t < DIM) { s_sum[t] = 0.f; s_sq[t] = 0.f; }
  __syncthreads();
  int c4 = (t & 31) * 4;
  int rg = t >> 5;
  float sum0=0,sum1=0,sum2=0,sum3=0, sq0=0,sq1=0,sq2=0,sq3=0;
  if (blockIdx.x < 512) {
    for (long row = (long)blockIdx.x * 8 + rg; row < N_NODES; row += 512L * 8) {
      float4 v = *reinterpret_cast<const float4*>(nf + row * DIM + c4);
      sum0 += v.x; sq0 += v.x * v.x;
      sum1 += v.y; sq1 += v.y * v.y;
      sum2 += v.z; sq2 += v.z * v.z;
      sum3 += v.w; sq3 += v.w * v.w;
    }
    atomicAdd(&s_sum[c4 + 0], sum0); atomicAdd(&s_sq[c4 + 0], sq0);
    atomicAdd(&s_sum[c4 + 1], sum1); atomicAdd(&s_sq[c4 + 1], sq1);
    atomicAdd(&s_sum[c4 + 2], sum2); atomicAdd(&s_sq[c4 + 2], sq2);
    atomicAdd(&s_sum[c4 + 3], sum3); atomicAdd(&s_sq[c4 + 3], sq3);
    __syncthreads();
    if (t < DIM) {
      atomicAdd(&stats_n[t], s_sum[t]);
      atomicAdd(&stats_n[DIM + t], s_sq[t]);
    }
  } else {
    long bid2 = blockIdx.x - 512;  // 0..2047
    for (long i = bid2 * 256 + t; i < N_EDGES; i += 2048L * 256) {
      atomicAdd(&deg[dst[i]], 1);
    }
    for (long row = bid2 * 8 + rg; row < N_EDGES; row += 2048L * 8) {
      float4 v = *reinterpret_cast<const float4*>(ef + row * DIM + c4);
      sum0 += v.x; sq0 += v.x * v.x;
      sum1 += v.y; sq1 += v.y * v.y;
      sum2 += v.z; sq2 += v.z * v.z;
      sum3 += v.w; sq3 += v.w * v.w;
      uint2 p;
      p.x = pack_bf2(v.x, v.y);
      p.y = pack_bf2(v.z, v.w);
      *reinterpret_cast<uint2*>(efb + row * DIM + c4) = p;
    }
    atomicAdd(&s_sum[c4 + 0], sum0); atomicAdd(&s_sq[c4 + 0], sq0);
    atomicAdd(&s_sum[c4 + 1], sum1); atomicAdd(&s_sq[c4 + 1], sq1);
    atomicAdd(&s_sum[c4 + 2], sum2); atomicAdd(&s_sq[c4 + 2], sq2);
    atomicAdd(&s_sum[c4 + 3], sum3); atomicAdd(&s_sq[c4 + 3], sq3);
    __syncthreads();
    if (t < DIM) {
      atomicAdd(&stats_e[t], s_sum[t]);
      atomicAdd(&stats_e[DIM + t], s_sq[t]);
    }
  }
}

// ---- fold7: blocks 0-3 BN-folded Wq/Wk/Wv/We; 4 OwT; 5 W2T; 6 CSR scan ----
#define SCAN_T 1024
#define PER_T 49
__global__ __launch_bounds__(1024) void fold7_kernel(
    const float* __restrict__ Wq, const float* __restrict__ Wk,
    const float* __restrict__ Wv, const float* __restrict__ We,
    const float* __restrict__ Ow, const float* __restrict__ W2,
    const float* __restrict__ stats_n, const float* __restrict__ stats_e,
    const float* __restrict__ g1n, const float* __restrict__ b1n,
    const float* __restrict__ g1e, const float* __restrict__ b1e, float inv_s,
    short* __restrict__ WqT, short* __restrict__ WkT,
    short* __restrict__ WvT, short* __restrict__ WeT,
    short* __restrict__ OwT, short* __restrict__ W2T,
    float* __restrict__ bq, float* __restrict__ bk,
    float* __restrict__ bv, float* __restrict__ be,
    const int* __restrict__ deg, int* __restrict__ row_start,
    int* __restrict__ cursor) {
  int b = blockIdx.x;
  int t = threadIdx.x;
  if (b == 6) {  // ---- CSR prefix scan ----
    __shared__ int ps[SCAN_T];
    int base = t * PER_T;
    int lsum = 0;
    int local[PER_T];
#pragma unroll
    for (int j = 0; j < PER_T; ++j) {
      int idx = base + j;
      int d = (idx < N_NODES) ? deg[idx] : 0;
      local[j] = lsum;
      lsum += d;
    }
    ps[t] = lsum;
    __syncthreads();
    for (int off = 1; off < SCAN_T; off <<= 1) {
      int v = (t >= off) ? ps[t - off] : 0;
      __syncthreads();
      ps[t] += v;
      __syncthreads();
    }
    int prefix = (t == 0) ? 0 : ps[t - 1];
#pragma unroll
    for (int j = 0; j < PER_T; ++j) {
      int idx = base + j;
      if (idx < N_NODES) {
        int v = prefix + local[j];
        row_start[idx] = v;
        cursor[idx] = v;
      }
    }
    if (t == SCAN_T - 1) row_start[N_NODES] = ps[SCAN_T - 1];
    return;
  }
  if (b == 4) {
    int d = t & 127, kg = t >> 7;
#pragma unroll
    for (int j = 0; j < 16; ++j) {
      int k = kg * 16 + j;
      OwT[d * DIM + k] = f2bf(Ow[k * DIM + d]);
    }
    return;
  }
  if (b == 5) {
    int d = t & 127, kg = t >> 7;
#pragma unroll
    for (int j = 0; j < 32; ++j) {
      int k = kg * 32 + j;
      W2T[d * 256 + k] = f2bf(W2[k * DIM + d]);
    }
    return;
  }
  __shared__ float red[8][DIM];
  __shared__ float sab[DIM], sbb[DIM];
  const float* W = (b == 0) ? Wq : (b == 1) ? Wk : (b == 2) ? Wv : We;
  const float* stats = (b == 3) ? stats_e : stats_n;
  const float* gamma = (b == 3) ? g1e : g1n;
  const float* beta  = (b == 3) ? b1e : b1n;
  float M            = (b == 3) ? (float)N_EDGES : (float)N_NODES;
  float scale = (b == 1) ? inv_s : 1.f;
  short* WT = (b == 0) ? WqT : (b == 1) ? WkT : (b == 2) ? WvT : WeT;
  float* bias = (b == 0) ? bq : (b == 1) ? bk : (b == 2) ? bv : be;
  if (t < DIM) {
    float mean = stats[t] / M;
    float var = stats[DIM + t] / M - mean * mean;
    float a = gamma[t] * rsqrtf(var + 1e-5f);
    sab[t] = a;
    sbb[t] = beta[t] - mean * a;
  }
  __syncthreads();
  int d = t & 127, kg = t >> 7;
  int ct = d >> 4, lr = d & 15;
  int L = (ct >> 1) * 32 + lr * 2 + (ct & 1);
  float bacc = 0.f;
#pragma unroll
  for (int j = 0; j < 16; ++j) {
    int k = kg * 16 + j;
    float wv = W[k * DIM + L];
    WT[d * DIM + k] = f2bf(scale * sab[k] * wv);
    bacc += sbb[k] * wv;
  }
  red[kg][d] = bacc;
  __syncthreads();
  if (kg == 0) {
    float s = 0.f;
#pragma unroll
    for (int j = 0; j < 8; ++j) s += red[j][d];
    bias[d] = scale * s;
  }
}

// ---- fold BN2 into W1: parallel (16 blocks x 256 thr, LDS bias reduce) ----
__global__ __launch_bounds__(256) void fold_w1_kernel(
    const float* __restrict__ W1, const float* __restrict__ stats_h,
    const float* __restrict__ g2, const float* __restrict__ b2,
    short* __restrict__ W1F, float* __restrict__ bias1) {
  __shared__ float sab[DIM], sbb[DIM];
  __shared__ float red[16][17];
  int t = threadIdx.x;
  if (t < DIM) {
    float mean = stats_h[t] / (float)N_NODES;
    float var = stats_h[DIM + t] / (float)N_NODES - mean * mean;
    float a = g2[t] * rsqrtf(var + 1e-5f);
    sab[t] = a;
    sbb[t] = b2[t] - mean * a;
  }
  __syncthreads();
  int dl = t & 15, kg = t >> 4;
  int d = blockIdx.x * 16 + dl;
  float bacc = 0.f;
#pragma unroll
  for (int j = 0; j < 8; ++j) {
    int k = kg * 8 + j;
    float wv = W1[k * 256 + d];
    W1F[d * DIM + k] = f2bf(sab[k] * wv);
    bacc += sbb[k] * wv;
  }
  red[dl][kg] = bacc;
  __syncthreads();
  if (kg == 0) {
    float s = 0.f;
#pragma unroll
    for (int j = 0; j < 16; ++j) s += red[dl][j];
    bias1[d] = s;
  }
}

// ---- load A fragments (4 k-steps) for 16 rows at m0, fp32->bf16 ----
__device__ inline void load_a_frags(const float* __restrict__ X, long m0,
                                    int lr, int lg, bf16x8 a[4]) {
#pragma unroll
  for (int ks = 0; ks < 4; ++ks) {
    const float* p = X + (m0 + lr) * DIM + ks * 32 + lg * 8;
    float4 v0 = *reinterpret_cast<const float4*>(p);
    float4 v1 = *reinterpret_cast<const float4*>(p + 4);
    bf16x8 af;
    af[0] = f2bf(v0.x); af[1] = f2bf(v0.y); af[2] = f2bf(v0.z); af[3] = f2bf(v0.w);
    af[4] = f2bf(v1.x); af[5] = f2bf(v1.y); af[6] = f2bf(v1.z); af[7] = f2bf(v1.w);
    a[ks] = af;
  }
}

// ---- fused scatter + QKV: blocks [0,782) QKV-MFMA; blocks [782, 3907) scatter ----
#define QKV_BLOCKS 782  // ceil(50000/64)
__global__ __launch_bounds__(256) void scatter_qkv_kernel(
    const float* __restrict__ nf,
    const short* __restrict__ WqT, const short* __restrict__ WkT, const short* __restrict__ WvT,
    const float* __restrict__ bq, const float* __restrict__ bk, const float* __restrict__ bv,
    ushort* __restrict__ Qb, ushort* __restrict__ Kb, ushort* __restrict__ Vb,
    const int* __restrict__ src, const int* __restrict__ dst,
    int* __restrict__ cursor, int2* __restrict__ csr) {
  int t = threadIdx.x;
  if (blockIdx.x >= QKV_BLOCKS) {
    int i = (blockIdx.x - QKV_BLOCKS) * 256 + t;
    int d = dst[i];
    int pos = atomicAdd(&cursor[d], 1);
    csr[pos] = make_int2(src[i], i);
    return;
  }
  int w = t >> 6, l = t & 63;
  int lr = l & 15, lg = l >> 4;
  long m0 = (long)blockIdx.x * 64 + w * 16;
  if (m0 >= N_NODES) return;
  bf16x8 a[4];
  load_a_frags(nf, m0, lr, lg, a);
  const short* Ws[3] = {WqT, WkT, WvT};
  const float* bs[3] = {bq, bk, bv};
  ushort* Os[3] = {Qb, Kb, Vb};
#pragma unroll 1
  for (int m = 0; m < 3; ++m) {
    const short* WT = Ws[m];
    f32x4 acc[8];
#pragma unroll
    for (int ct = 0; ct < 8; ++ct) acc[ct] = (f32x4){0.f, 0.f, 0.f, 0.f};
    __builtin_amdgcn_s_setprio(1);
#pragma unroll
    for (int ct = 0; ct < 8; ++ct) {
#pragma unroll
      for (int ks = 0; ks < 4; ++ks) {
        bf16x8 b = *reinterpret_cast<const bf16x8*>(WT + (ct * 16 + lr) * DIM + ks * 32 + lg * 8);
        acc[ct] = __builtin_amdgcn_mfma_f32_16x16x32_bf16(a[ks], b, acc[ct], 0, 0, 0);
      }
    }
    __builtin_amdgcn_s_setprio(0);
    const float* bb = bs[m];
    ushort* O = Os[m];
#pragma unroll
    for (int h = 0; h < 4; ++h) {
      float b0 = bb[(2 * h) * 16 + lr];
      float b1 = bb[(2 * h + 1) * 16 + lr];
#pragma unroll
      for (int r = 0; r < 4; ++r) {
        uint u = pack_bf2(acc[2 * h][r] + b0, acc[2 * h + 1][r] + b1);
        *reinterpret_cast<uint*>(O + (m0 + lg * 4 + r) * DIM + h * 32 + lr * 2) = u;
      }
    }
  }
}

// ------- edge score: bf16 ef (nontemporal), setprio around MFMA, bf16-packed s -------
#define ES_GRID 2048
__global__ __launch_bounds__(256) void edge_score_kernel(
    const ushort* __restrict__ efb,
    const int* __restrict__ src, const int* __restrict__ dst,
    const short* __restrict__ WeT, const float* __restrict__ be,
    const ushort* __restrict__ Qb, const ushort* __restrict__ Kb,
    uint2* __restrict__ s_pack) {
  const int NT = N_EDGES / 64;
  int t = threadIdx.x;
  int w = t >> 6, l = t & 63;
  int lr = l & 15, lg = l >> 4;
  float ber[8];
#pragma unroll
  for (int ct = 0; ct < 8; ++ct) ber[ct] = be[ct * 16 + lr];

  for (int tile = blockIdx.x; tile < NT; tile += gridDim.x) {
    long m0 = (long)tile * 64 + w * 16;
    long eb = m0 + lg * 4;
    int4 s4 = *reinterpret_cast<const int4*>(src + eb);
    int4 d4 = *reinterpret_cast<const int4*>(dst + eb);
    int sn[4] = {s4.x, s4.y, s4.z, s4.w};
    int dn[4] = {d4.x, d4.y, d4.z, d4.w};
    uint Kg[4][4], Qg[4][4];
#pragma unroll
    for (int r = 0; r < 4; ++r) {
#pragma unroll
      for (int h = 0; h < 4; ++h) {
        Kg[r][h] = *reinterpret_cast<const uint*>(Kb + (long)sn[r] * DIM + h * 32 + lr * 2);
        Qg[r][h] = *reinterpret_cast<const uint*>(Qb + (long)dn[r] * DIM + h * 32 + lr * 2);
      }
    }
    bf16x8 a[4];
#pragma unroll
    for (int ks = 0; ks < 4; ++ks) {
      a[ks] = __builtin_nontemporal_load(
          reinterpret_cast<const bf16x8*>(efb + (m0 + lr) * DIM + ks * 32 + lg * 8));
    }
    f32x4 acc[8];
#pragma unroll
    for (int ct = 0; ct < 8; ++ct) acc[ct] = (f32x4){0.f, 0.f, 0.f, 0.f};
    __builtin_amdgcn_s_setprio(1);
#pragma unroll
    for (int ct = 0; ct < 8; ++ct) {
#pragma unroll
      for (int ks = 0; ks < 4; ++ks) {
        bf16x8 b = *reinterpret_cast<const bf16x8*>(WeT + (ct * 16 + lr) * DIM + ks * 32 + lg * 8);
        acc[ct] = __builtin_amdgcn_mfma_f32_16x16x32_bf16(a[ks], b, acc[ct], 0, 0, 0);
      }
    }
    __builtin_amdgcn_s_setprio(0);
#pragma unroll
    for (int r = 0; r < 4; ++r) {
      float hs0, hs1, hs2, hs3;
      {
        float h0, h1, h2, h3;
#pragma unroll
        for (int h = 0; h < 4; ++h) {
          float k0 = bflo(Kg[r][h]), k1 = bfhi(Kg[r][h]);
          float q0 = bflo(Qg[r][h]), q1 = bfhi(Qg[r][h]);
          float pe0 = acc[2 * h][r] + ber[2 * h];
          float pe1 = acc[2 * h + 1][r] + ber[2 * h + 1];
          float v = fminf(fmaxf(k0 * q0, -5.f), 5.f) * pe0
                  + fminf(fmaxf(k1 * q1, -5.f), 5.f) * pe1;
          if (h == 0) h0 = v; else if (h == 1) h1 = v; else if (h == 2) h2 = v; else h3 = v;
        }
        hs0 = h0; hs1 = h1; hs2 = h2; hs3 = h3;
      }
#pragma unroll
      for (int m2 = 8; m2 >= 1; m2 >>= 1) {
        hs0 += __shfl_xor(hs0, m2);
        hs1 += __shfl_xor(hs1, m2);
        hs2 += __shfl_xor(hs2, m2);
        hs3 += __shfl_xor(hs3, m2);
      }
      if (lr == 0) {
        float e0 = __expf(fminf(fmaxf(hs0, -5.f), 5.f));
        float e1 = __expf(fminf(fmaxf(hs1, -5.f), 5.f));
        float e2 = __expf(fminf(fmaxf(hs2, -5.f), 5.f));
        float e3 = __expf(fminf(fmaxf(hs3, -5.f), 5.f));
        uint2 p;
        p.x = pack_bf2(e0, e1);
        p.y = pack_bf2(e2, e3);
        s_pack[eb + r] = p;
      }
    }
  }
}

// ------- aggregate: one wave per dst node, 8-deep batched loads; bf16 s + output -------
__global__ __launch_bounds__(256) void aggregate_kernel(
    const int* __restrict__ row_start, const int2* __restrict__ csr,
    const uint2* __restrict__ s_pack, const ushort* __restrict__ Vb,
    ushort* __restrict__ haggb) {
  int t = threadIdx.x;
  int w = t >> 6, l = t & 63;
  int n = blockIdx.x * 4 + w;
  int r0 = row_start[n], r1 = row_start[n + 1];
  int h = l >> 4;
  float a0 = 0.f, a1 = 0.f, zacc = 0.f;
  int idx = r0;
  for (; idx + 8 <= r1; idx += 8) {
    int2 rec[8];
#pragma unroll
    for (int j = 0; j < 8; ++j) rec[j] = csr[idx + j];
    float sv[8]; uint uv[8];
#pragma unroll
    for (int j = 0; j < 8; ++j) {
      uint2 sp = s_pack[rec[j].y];
      uint uw = (h < 2) ? sp.x : sp.y;
      sv[j] = (h & 1) ? bfhi(uw) : bflo(uw);
      uv[j] = *reinterpret_cast<const uint*>(Vb + (long)rec[j].x * DIM + l * 2);
    }
#pragma unroll
    for (int j = 0; j < 8; ++j) {
      a0 += sv[j] * bflo(uv[j]);
      a1 += sv[j] * bfhi(uv[j]);
      zacc += sv[j];
    }
  }
  for (; idx < r1; ++idx) {
    int2 ra = csr[idx];
    uint2 sp = s_pack[ra.y];
    uint uw = (h < 2) ? sp.x : sp.y;
    float sa = (h & 1) ? bfhi(uw) : bflo(uw);
    uint ua = *reinterpret_cast<const uint*>(Vb + (long)ra.x * DIM + l * 2);
    a0 += sa * bflo(ua);
    a1 += sa * bfhi(ua);
    zacc += sa;
  }
  float inv = 1.f / (zacc + 1e-6f);
  *reinterpret_cast<uint*>(haggb + (long)n * DIM + l * 2) = pack_bf2(a0 * inv, a1 * inv);
}

// ---------------- attnout via MFMA: hres = h_in1 + hagg @ Ow + Ob; BN2 stats ----------------
__global__ __launch_bounds__(256) void attnout_mfma_kernel(
    const ushort* __restrict__ haggb, const short* __restrict__ OwT,
    const float* __restrict__ Ob, const float* __restrict__ h_in1,
    float* __restrict__ hres, float* __restrict__ stats2) {
  int t = threadIdx.x;
  int w = t >> 6, l = t & 63;
  int lr = l & 15, lg = l >> 4;
  long m0 = (long)blockIdx.x * 64 + w * 16;
  if (m0 >= N_NODES) return;
  bf16x8 a[4];
#pragma unroll
  for (int ks = 0; ks < 4; ++ks) {
    a[ks] = *reinterpret_cast<const bf16x8*>(haggb + (m0 + lr) * DIM + ks * 32 + lg * 8);
  }
  f32x4 acc[8];
#pragma unroll
  for (int ct = 0; ct < 8; ++ct) acc[ct] = (f32x4){0.f, 0.f, 0.f, 0.f};
#pragma unroll
  for (int ct = 0; ct < 8; ++ct) {
#pragma unroll
    for (int ks = 0; ks < 4; ++ks) {
      bf16x8 b = *reinterpret_cast<const bf16x8*>(OwT + (ct * 16 + lr) * DIM + ks * 32 + lg * 8);
      acc[ct] = __builtin_amdgcn_mfma_f32_16x16x32_bf16(a[ks], b, acc[ct], 0, 0, 0);
    }
  }
#pragma unroll
  for (int ct = 0; ct < 8; ++ct) {
    float ob = Ob[ct * 16 + lr];
    float ls = 0.f, lq = 0.f;
#pragma unroll
    for (int r = 0; r < 4; ++r) {
      long idx = (m0 + lg * 4 + r) * DIM + ct * 16 + lr;
      float hv = h_in1[idx] + acc[ct][r] + ob;
      hres[idx] = hv;
      ls += hv; lq += hv * hv;
    }
    ls += __shfl_xor(ls, 16); ls += __shfl_xor(ls, 32);
    lq += __shfl_xor(lq, 16); lq += __shfl_xor(lq, 32);
    if (lg == 0) {
      atomicAdd(&stats2[ct * 16 + lr], ls);
      atomicAdd(&stats2[DIM + ct * 16 + lr], lq);
    }
  }
}

// ---------------- MLP via MFMA: out = hres + silu(BN2(hres) @ W1) @ W2 ----------------
__global__ __launch_bounds__(256) void mlp_mfma_kernel(
    const float* __restrict__ hres, const short* __restrict__ W1F,
    const float* __restrict__ bias1, const short* __restrict__ W2T,
    float* __restrict__ out) {
  __shared__ short mid[64][264];  // padded: 2-way bank conflicts only
  int t = threadIdx.x;
  int w = t >> 6, l = t & 63;
  int lr = l & 15, lg = l >> 4;
  long m0 = (long)blockIdx.x * 64 + w * 16;
  if (m0 >= N_NODES) return;
  bf16x8 a1[4];
  load_a_frags(hres, m0, lr, lg, a1);
#pragma unroll
  for (int ct = 0; ct < 16; ++ct) {
    f32x4 acc = (f32x4){0.f, 0.f, 0.f, 0.f};
#pragma unroll
    for (int ks = 0; ks < 4; ++ks) {
      bf16x8 b = *reinterpret_cast<const bf16x8*>(W1F + (ct * 16 + lr) * DIM + ks * 32 + lg * 8);
      acc = __builtin_amdgcn_mfma_f32_16x16x32_bf16(a1[ks], b, acc, 0, 0, 0);
    }
    float bb = bias1[ct * 16 + lr];
#pragma unroll
    for (int r = 0; r < 4; ++r) {
      float x = acc[r] + bb;
      float sl = x / (1.f + __expf(-x));
      mid[w * 16 + lg * 4 + r][ct * 16 + lr] = f2bf(sl);
    }
  }
  bf16x8 a2[8];
#pragma unroll
  for (int ks = 0; ks < 8; ++ks) {
    a2[ks] = *reinterpret_cast<const bf16x8*>(&mid[w * 16 + lr][ks * 32 + lg * 8]);
  }
#pragma unroll
  for (int ct = 0; ct < 8; ++ct) {
    f32x4 acc = (f32x4){0.f, 0.f, 0.f, 0.f};
#pragma unroll
    for (int ks = 0; ks < 8; ++ks) {
      bf16x8 b = *reinterpret_cast<const bf16x8*>(W2T + (ct * 16 + lr) * 256 + ks * 32 + lg * 8);
      acc = __builtin_amdgcn_mfma_f32_16x16x32_bf16(a2[ks], b, acc, 0, 0, 0);
    }
#pragma unroll
    for (int r = 0; r < 4; ++r) {
      long idx = (m0 + lg * 4 + r) * DIM + ct * 16 + lr;
      out[idx] = hres[idx] + acc[r];
    }
  }
}

extern "C" void kernel_launch(void* const* d_in, const int* in_sizes, int n_in,
                              void* d_out, int out_size, void* d_ws, size_t ws_size,
                              hipStream_t stream) {
  const float* node_feats = (const float*)d_in[0];
  const float* edge_feats = (const float*)d_in[1];
  const int* src = (const int*)d_in[2];
  const int* dst = (const int*)d_in[3];
  const float* Wq = (const float*)d_in[4];
  const float* Wk = (const float*)d_in[5];
  const float* Wv = (const float*)d_in[6];
  const float* We = (const float*)d_in[7];
  const float* Ow = (const float*)d_in[8];
  const float* Ob = (const float*)d_in[9];
  const float* g1n = (const float*)d_in[10];
  const float* b1n = (const float*)d_in[11];
  const float* g1e = (const float*)d_in[12];
  const float* b1e = (const float*)d_in[13];
  const float* g2 = (const float*)d_in[14];
  const float* b2 = (const float*)d_in[15];
  const float* W1 = (const float*)d_in[16];
  const float* W2 = (const float*)d_in[17];
  float* out = (float*)d_out;
  float* w = (float*)d_ws;

  float* bq = w + 1536;
  float* bk = w + 1664;
  float* bv = w + 1792;
  float* be = w + 1920;
  short* WqT = (short*)(w + 2048);    // 128x128 bf16 = 8192 floats
  short* WkT = (short*)(w + 10240);
  short* WvT = (short*)(w + 18432);
  short* WeT = (short*)(w + 26624);
  short* OwT = (short*)(w + 34816);   // 8192 floats
  short* W1F = (short*)(w + 43008);   // 256x128 bf16 = 16384 floats
  short* W2T = (short*)(w + 59392);   // 128x256 bf16 = 16384 floats
  float* bias1 = w + 75776;           // 256
  ushort* Qb = (ushort*)(w + 76032);  // N*128 bf16 = 3.2M floats
  ushort* Kb = (ushort*)(w + 3276032);
  ushort* Vb = (ushort*)(w + 6476032);
  uint2* s_pack = (uint2*)(w + 9676032);      // E uint2 = 1.6M floats
  // --- contiguous zeroed region: deg + stats (single memset) ---
  int* deg = (int*)(w + 12876032);            // 50048 ints
  float* stats_n = w + 12926080;              // deg + 50048
  float* stats_e = stats_n + 256;
  float* stats_h = stats_e + 256;
  int* row_start = (int*)(stats_h + 256);     // 50064 ints (not zeroed)
  int* cursor = row_start + 50064;            // 50048 ints (not zeroed)
  int2* csr = (int2*)(cursor + 50048);        // E int2, starts 13026960
  ushort* efb = (ushort*)(w + 16227008);      // E*128 bf16 = 51.2M floats
  ushort* haggb = (ushort*)(w + 76032);       // overlays Qb (dead after edge_score)

  const float inv_s = 0.17677669529663687f;  // 1/sqrt(32), folded into K

  hipMemsetAsync(deg, 0, (50048 + 768) * sizeof(int), stream);

  stats_all_kernel<<<2560, 256, 0, stream>>>(
      node_feats, edge_feats, dst, stats_n, stats_e, deg, efb);
  fold7_kernel<<<7, 1024, 0, stream>>>(Wq, Wk, Wv, We, Ow, W2, stats_n, stats_e,
                                       g1n, b1n, g1e, b1e, inv_s,
                                       WqT, WkT, WvT, WeT, OwT, W2T, bq, bk, bv, be,
                                       deg, row_start, cursor);
  scatter_qkv_kernel<<<QKV_BLOCKS + N_EDGES / 256, 256, 0, stream>>>(
      node_feats, WqT, WkT, WvT, bq, bk, bv, Qb, Kb, Vb, src, dst, cursor, csr);
  edge_score_kernel<<<ES_GRID, 256, 0, stream>>>(
      efb, src, dst, WeT, be, Qb, Kb, s_pack);
  aggregate_kernel<<<N_NODES / 4, 256, 0, stream>>>(row_start, csr, s_pack, Vb, haggb);
  attnout_mfma_kernel<<<(N_NODES + 63) / 64, 256, 0, stream>>>(
      haggb, OwT, Ob, node_feats, out, stats_h);
  fold_w1_kernel<<<16, 256, 0, stream>>>(W1, stats_h, g2, b2, W1F, bias1);
  mlp_mfma_kernel<<<(N_NODES + 63) / 64, 256, 0, stream>>>(out, W1F, bias1, W2T, out);
}